// Round 3
// baseline (1995.938 us; speedup 1.0000x reference)
//
#include <hip/hip_runtime.h>
#include <hip/hip_bf16.h>
#include <math.h>

typedef __hip_bfloat16 bf16;
typedef __bf16 bf16x8 __attribute__((ext_vector_type(8)));
typedef float f32x4 __attribute__((ext_vector_type(4)));

__device__ __forceinline__ float b2f(bf16 v){ return __bfloat162float(v); }
__device__ __forceinline__ bf16  f2b(float v){ return __float2bfloat16(v); }

// tanh-form gelu (~6 VALU ops); max |diff vs erf-gelu| ~1e-3
__device__ __forceinline__ float gelu_f(float v){
    float y = v * (1.f + 0.044715f * v * v);
    return v / (1.f + __expf(-1.5957691216057308f * y));
}

// async global->LDS, 16B per lane; LDS dest = wave-uniform base + lane*16
__device__ __forceinline__ void gl_lds16(const bf16* g, bf16* l) {
    __builtin_amdgcn_global_load_lds((const __attribute__((address_space(1))) unsigned int*)g,
                                     (__attribute__((address_space(3))) unsigned int*)l, 16, 0, 0);
}

__device__ __forceinline__ uint2 pack4bf(const float* v){
    union { unsigned short e[4]; uint2 u; } pk;
    #pragma unroll
    for (int r = 0; r < 4; r++) pk.e[r] = __builtin_bit_cast(unsigned short, f2b(v[r]));
    return pk.u;
}

// raw barrier without the compiler's vmcnt(0) drain; sched fences pin phase structure
__device__ __forceinline__ void phase_bar() {
    __builtin_amdgcn_sched_barrier(0);
    __builtin_amdgcn_s_barrier();
    __builtin_amdgcn_sched_barrier(0);
}

// ---------------- deck means ----------------
__global__ __launch_bounds__(256) void deckmean_k(const int* __restrict__ deck, const int* __restrict__ opp,
                                                  const float* __restrict__ tok, float* __restrict__ deckm)
{
    int b = blockIdx.x, w = blockIdx.y;
    const int* dk = (w ? opp : deck) + b * 8;
    int idx[8];
    #pragma unroll
    for (int j = 0; j < 8; j++) idx[j] = dk[j];
    float* out = deckm + (size_t)(w * 16 + b) * 768;
    for (int d = threadIdx.x; d < 768; d += 256) {
        float s = 0.f;
        #pragma unroll
        for (int j = 0; j < 8; j++) s += tok[(size_t)idx[j] * 768 + d];
        out[d] = s * 0.125f;
    }
}

// ---------------- mask + last_idx ----------------
__global__ __launch_bounds__(512) void mask_k(const int* __restrict__ cards, int* __restrict__ maskb,
                                              int* __restrict__ lastidx)
{
    int b = blockIdx.x, t = threadIdx.x;
    int m = (cards[b * 512 + t] != 0) ? 1 : 0;
    maskb[b * 512 + t] = m;
    __shared__ int red[512];
    red[t] = m; __syncthreads();
    for (int st = 256; st > 0; st >>= 1) { if (t < st) red[t] += red[t + st]; __syncthreads(); }
    if (t == 0) {
        int cnt = red[0];
        if (cnt == 0) { maskb[b * 512] = 1; cnt = 1; }  // all-pad fix
        lastidx[b] = cnt - 1;
    }
}

// ---------------- embedding sum -> fp32 residual stream ----------------
__global__ __launch_bounds__(256) void embed_k(const int* __restrict__ cards, const int* __restrict__ players,
                                               const float* __restrict__ tok, const float* __restrict__ pemb,
                                               const float* __restrict__ pos, const float* __restrict__ deckm,
                                               float* __restrict__ x)
{
    int t = blockIdx.x;
    int b = t >> 9, ti = t & 511;
    int cd = cards[t];
    int p = players[t]; p = p < 0 ? 0 : (p > 1 ? 1 : p);
    const float* tr  = tok  + (size_t)cd * 768;
    const float* pr  = pemb + (size_t)p  * 768;
    const float* po  = pos  + (size_t)ti * 768;
    const float* dm = deckm + (size_t)b * 768;
    const float* om = deckm + (size_t)(16 + b) * 768;
    float* xr = x + (size_t)t * 768;
    for (int d = threadIdx.x; d < 768; d += 256)
        xr[d] = tr[d] + pr[d] + po[d] + dm[d] + om[d];
}

// ---------------- layernorm (vectorized): fp32 in -> bf16 out, 192 thr/row ----------------
__global__ __launch_bounds__(192) void ln_k(const float* __restrict__ x, const float* __restrict__ s,
                                            const float* __restrict__ b, bf16* __restrict__ out)
{
    int row = blockIdx.x, tid = threadIdx.x;
    float4 v = ((const float4*)(x + (size_t)row * 768))[tid];
    float sum = v.x + v.y + v.z + v.w;
    float sq  = v.x * v.x + v.y * v.y + v.z * v.z + v.w * v.w;
    #pragma unroll
    for (int off = 32; off > 0; off >>= 1) {
        sum += __shfl_xor(sum, off, 64);
        sq  += __shfl_xor(sq,  off, 64);
    }
    __shared__ float red[6];
    int wv = tid >> 6;
    if ((tid & 63) == 0) { red[wv] = sum; red[3 + wv] = sq; }
    __syncthreads();
    float S = red[0] + red[1] + red[2];
    float Q = red[3] + red[4] + red[5];
    float mean = S * (1.f / 768.f);
    float var  = Q * (1.f / 768.f) - mean * mean;
    float rstd = rsqrtf(var + 1e-5f);
    float4 sv = ((const float4*)s)[tid];
    float4 bv = ((const float4*)b)[tid];
    float o[4] = { (v.x - mean) * rstd * sv.x + bv.x, (v.y - mean) * rstd * sv.y + bv.y,
                   (v.z - mean) * rstd * sv.z + bv.z, (v.w - mean) * rstd * sv.w + bv.w };
    ((uint2*)(out + (size_t)row * 768))[tid] = pack4bf(o);
}

// ---------------- weight transpose+downcast: 64x64 tiles, in-register 4x4 transpose ----------------
// tiles: qkv 12x36=432, proj 12x12=144, fc1 12x48=576, fc2 48x12=576 -> 1728 blocks
__global__ __launch_bounds__(256) void transpose4_k(const float* __restrict__ qw, const float* __restrict__ pw,
                                                    const float* __restrict__ f1, const float* __restrict__ f2,
                                                    bf16* __restrict__ oq, bf16* __restrict__ op,
                                                    bf16* __restrict__ o1, bf16* __restrict__ o2)
{
    int t = blockIdx.x;
    const float* in; bf16* out; int K, N, nbx;
    if (t < 432)       { in = qw; out = oq; K = 768;  N = 2304; nbx = 36; }
    else if (t < 576)  { in = pw; out = op; K = 768;  N = 768;  t -= 432;  nbx = 12; }
    else if (t < 1152) { in = f1; out = o1; K = 768;  N = 3072; t -= 576;  nbx = 48; }
    else               { in = f2; out = o2; K = 3072; N = 768;  t -= 1152; nbx = 12; }
    int n0 = (t % nbx) * 64, k0 = (t / nbx) * 64;
    int kq = threadIdx.x & 15, nq = threadIdx.x >> 4;
    float4 rr[4];
    #pragma unroll
    for (int r = 0; r < 4; r++)
        rr[r] = *(const float4*)&in[(size_t)(k0 + kq * 4 + r) * N + n0 + nq * 4];
    const float* fp = (const float*)rr;
    #pragma unroll
    for (int c = 0; c < 4; c++) {
        float v[4] = { fp[c], fp[4 + c], fp[8 + c], fp[12 + c] };
        *(uint2*)&out[(size_t)(n0 + nq * 4 + c) * K + k0 + kq * 4] = pack4bf(v);
    }
}

// ---------------- MFMA GEMM 256x256, 8-phase pipelined, 2-deep half-tile prefetch ----------------
// 512 thr = 8 waves (2M x 4N), per-wave 128x64 output = acc[8][4].
// Phases rb-major: P0 (rows-lo,kk0) P1 (rows-lo,kk1) P2 (rows-hi,kk0) P3 (rows-hi,kk1);
// B-frags for kk0/kk1 cached in regs across the tile (24 ds_read_b128/tile).
// Staging depth: B(t+1)+A-high(t+1) at P0 (4-phase cover, into idle buf);
// A-low(t+2) at P2 into CURRENT buf (region dead after P1's barrier -> race-free; 6-phase cover).
// One wait per tile at end-P3: vmcnt(2) (leaves A-low(t+2) in flight). Never drains mid-loop.
__global__ __launch_bounds__(512, 2) void gemm256_k(const bf16* __restrict__ A, const bf16* __restrict__ BT,
                                                    const float* __restrict__ bias, bf16* __restrict__ out,
                                                    int N, int K, int act, int nbn)
{
    __shared__ __align__(16) bf16 Asb[2][256 * 64];
    __shared__ __align__(16) bf16 Bsb[2][256 * 64];

    const int tid  = threadIdx.x;
    const int lane = tid & 63, wid = tid >> 6;
    const int quad = lane >> 4, l16 = lane & 15;
    const int wr = wid >> 2, wc = wid & 3;
    const int xr  = l16 & 7;
    const int cg0 = quad ^ xr;          // physical col-group for kk=0
    const int cg1 = cg0 ^ 4;            // physical col-group for kk=32

    const int nwg  = gridDim.x;                       // multiple of 8 for all call sites
    const int wgid = ((int)blockIdx.x & 7) * (nwg >> 3) + ((int)blockIdx.x >> 3);
    const int mt = wgid / nbn, nt = wgid - mt * nbn;
    const int m0 = mt * 256, n0 = nt * 256;

    // per-thread staging source: sweep s covers tile rows s*64..s*64+63; each wave 8 rows/sweep
    const int srow = wid * 8 + (lane >> 3);
    const int scg  = (lane & 7) ^ (lane >> 3);        // pre-swizzled global col-group
    const bf16* sa[4]; const bf16* sb[4];
    #pragma unroll
    for (int s = 0; s < 4; s++) {
        sa[s] = A  + (size_t)(m0 + s * 64 + srow) * K + scg * 8;
        sb[s] = BT + (size_t)(n0 + s * 64 + srow) * K + scg * 8;
    }

#define STG_A(s, b) gl_lds16(sa[s], &Asb[b][((s) * 64 + wid * 8) * 64])
#define STG_B(s, b) gl_lds16(sb[s], &Bsb[b][((s) * 64 + wid * 8) * 64])
#define ADV { _Pragma("unroll") for (int s = 0; s < 4; s++) { sa[s] += 64; sb[s] += 64; } }
#define LD_B(BV, cg) { _Pragma("unroll") for (int ni = 0; ni < 4; ni++) \
    BV[ni] = __builtin_bit_cast(bf16x8, *(const uint4*)&Bc[(wc * 64 + ni * 16 + l16) * 64 + (cg) * 8]); }
#define LD_A(rb, cg) { _Pragma("unroll") for (int mi = 0; mi < 4; mi++) \
    afv[mi] = __builtin_bit_cast(bf16x8, *(const uint4*)&Ac[(wr * 128 + (rb) + mi * 16 + l16) * 64 + (cg) * 8]); }
#define MFMA16(MB, BV) { _Pragma("unroll") for (int mi = 0; mi < 4; mi++) \
    _Pragma("unroll") for (int ni = 0; ni < 4; ni++) \
        acc[(MB) + mi][ni] = __builtin_amdgcn_mfma_f32_16x16x32_bf16(BV[ni], afv[mi], acc[(MB) + mi][ni], 0, 0, 0); }

    f32x4 acc[8][4] = {};
    const int NKT = K >> 6;

    // prologue: tile0 (8 loads) into buf0; A-low(1) (2 loads) into buf1
    STG_A(0, 0); STG_A(2, 0); STG_A(1, 0); STG_A(3, 0);
    STG_B(0, 0); STG_B(1, 0); STG_B(2, 0); STG_B(3, 0);
    ADV;                                   // -> tile 1
    if (NKT > 1) {
        STG_A(0, 1); STG_A(2, 1);
        asm volatile("s_waitcnt vmcnt(2)" ::: "memory");   // tile0's 8 landed
    } else {
        asm volatile("s_waitcnt vmcnt(0)" ::: "memory");
    }
    phase_bar();

    for (int kt = 0; kt < NKT; kt++) {
        const bf16* Ac = Asb[kt & 1];
        const bf16* Bc = Bsb[kt & 1];
        const int cur = kt & 1, oth = cur ^ 1;
        const bool pf1 = (kt + 1 < NKT), pf2 = (kt + 2 < NKT);
        bf16x8 bfv0[4], bfv1[4], afv[4];

        // ---------- P0: rows-lo, kk0; stage B(t+1)+A-high(t+1) -> idle buf ----------
        LD_B(bfv0, cg0); LD_A(0, cg0);
        if (pf1) {
            STG_B(0, oth); STG_B(1, oth); STG_B(2, oth); STG_B(3, oth);
            STG_A(1, oth); STG_A(3, oth);
        }
        ADV;                               // sa/sb -> tile kt+2
        phase_bar();
        __builtin_amdgcn_s_setprio(1); MFMA16(0, bfv0); __builtin_amdgcn_s_setprio(0);
        phase_bar();

        // ---------- P1: rows-lo, kk1 ----------
        LD_B(bfv1, cg1); LD_A(0, cg1);
        phase_bar();
        __builtin_amdgcn_s_setprio(1); MFMA16(0, bfv1); __builtin_amdgcn_s_setprio(0);
        phase_bar();

        // ---------- P2: rows-hi, kk0; stage A-low(t+2) -> CURRENT buf (dead after P1 bar) ----------
        LD_A(64, cg0);
        if (pf2) { STG_A(0, cur); STG_A(2, cur); }
        phase_bar();
        __builtin_amdgcn_s_setprio(1); MFMA16(4, bfv0); __builtin_amdgcn_s_setprio(0);
        phase_bar();

        // ---------- P3: rows-hi, kk1; single per-tile wait ----------
        LD_A(64, cg1);
        phase_bar();
        __builtin_amdgcn_s_setprio(1); MFMA16(4, bfv1); __builtin_amdgcn_s_setprio(0);
        if (pf2)      { asm volatile("s_waitcnt vmcnt(2)" ::: "memory"); }  // t+1 fully landed
        else if (pf1) { asm volatile("s_waitcnt vmcnt(0)" ::: "memory"); }  // drain for last tile
        phase_bar();
    }

    float4 bv[4];
    #pragma unroll
    for (int ni = 0; ni < 4; ni++)
        bv[ni] = *(const float4*)&bias[n0 + wc * 64 + ni * 16 + quad * 4];

    #pragma unroll
    for (int mi = 0; mi < 8; mi++) {
        const int m = m0 + wr * 128 + mi * 16 + l16;
        #pragma unroll
        for (int ni = 0; ni < 4; ni++) {
            const int nb2 = n0 + wc * 64 + ni * 16 + quad * 4;
            float v[4] = { acc[mi][ni][0] + bv[ni].x, acc[mi][ni][1] + bv[ni].y,
                           acc[mi][ni][2] + bv[ni].z, acc[mi][ni][3] + bv[ni].w };
            if (act) {
                #pragma unroll
                for (int r = 0; r < 4; r++) v[r] = gelu_f(v[r]);
            }
            *(uint2*)&out[(size_t)m * N + nb2] = pack4bf(v);
        }
    }
#undef STG_A
#undef STG_B
#undef ADV
#undef LD_B
#undef LD_A
#undef MFMA16
}

// ---------------- MFMA GEMM 256x128 narrow-N (proj, fc2), pipelined, fp32 residual RMW ----------------
// 512 thr = 8 waves (4M x 2N), per-wave 64x64 output = acc[4][4]; 2 phases x 16 MFMA per K-tile.
// Triple-buffered LDS (3 x 48 KiB = 144 KiB), 2-deep prefetch: P0 of kt stages tile kt+2;
// end-of-P1 wait vmcnt(6) publishes tile kt+1 while tile kt+2's 6 loads stay in flight.
// Same both-sides XOR swizzle as gemm256_k. Requires NKT % 3 == 0 (call sites: K=768, 3072).
__global__ __launch_bounds__(512, 2) void gemmn128_k(const bf16* __restrict__ A, const bf16* __restrict__ BT,
                                                     const float* __restrict__ bias, float* __restrict__ x,
                                                     int N, int K, int nbn)
{
    __shared__ __align__(16) bf16 Asb[3][256 * 64];
    __shared__ __align__(16) bf16 Bsb[3][128 * 64];

    const int tid  = threadIdx.x;
    const int lane = tid & 63, wid = tid >> 6;
    const int quad = lane >> 4, l16 = lane & 15;
    const int wr = wid >> 1, wc = wid & 1;
    const int cg0 = quad ^ (l16 & 7);
    const int cg1 = cg0 ^ 4;

    const int nwg  = gridDim.x;                        // multiple of 8
    const int wgid = ((int)blockIdx.x & 7) * (nwg >> 3) + ((int)blockIdx.x >> 3);
    const int mt = wgid / nbn, nt = wgid - mt * nbn;
    const int m0 = mt * 256, n0 = nt * 128;

    const int srow = wid * 8 + (lane >> 3);
    const int scg  = (lane & 7) ^ (lane >> 3);         // pre-swizzled global col-group
    const bf16* sa[4]; const bf16* sb[2];
    #pragma unroll
    for (int s = 0; s < 4; s++) sa[s] = A  + (size_t)(m0 + s * 64 + srow) * K + scg * 8;
    #pragma unroll
    for (int s = 0; s < 2; s++) sb[s] = BT + (size_t)(n0 + s * 64 + srow) * K + scg * 8;

#define NSTG_A(s, b) gl_lds16(sa[s], &Asb[b][((s) * 64 + wid * 8) * 64])
#define NSTG_B(s, b) gl_lds16(sb[s], &Bsb[b][((s) * 64 + wid * 8) * 64])
#define NSTG6(b) { NSTG_A(0, b); NSTG_A(1, b); NSTG_A(2, b); NSTG_A(3, b); NSTG_B(0, b); NSTG_B(1, b); }
#define NADV { _Pragma("unroll") for (int s = 0; s < 4; s++) sa[s] += 64; sb[0] += 64; sb[1] += 64; }
#define NLD(cg, b) { _Pragma("unroll") for (int i = 0; i < 4; i++) { \
    bfv[i] = __builtin_bit_cast(bf16x8, *(const uint4*)&Bsb[b][(wc * 64 + i * 16 + l16) * 64 + (cg) * 8]); \
    afv[i] = __builtin_bit_cast(bf16x8, *(const uint4*)&Asb[b][(wr * 64 + i * 16 + l16) * 64 + (cg) * 8]); } }
#define NMFMA { _Pragma("unroll") for (int mi = 0; mi < 4; mi++) \
    _Pragma("unroll") for (int ni = 0; ni < 4; ni++) \
        acc[mi][ni] = __builtin_amdgcn_mfma_f32_16x16x32_bf16(bfv[ni], afv[mi], acc[mi][ni], 0, 0, 0); }
// one K-tile: P0 {ds_read cg0 | stage kt+2 -> ST} MFMA16; P1 {ds_read cg1} MFMA16, publish kt+1
#define NITER(CUR, ST) { \
    const bool pf = (kt + 2 < NKT); \
    NLD(cg0, CUR); \
    if (pf) { NSTG6(ST); NADV; } \
    phase_bar(); \
    __builtin_amdgcn_s_setprio(1); NMFMA; __builtin_amdgcn_s_setprio(0); \
    phase_bar(); \
    NLD(cg1, CUR); \
    phase_bar(); \
    __builtin_amdgcn_s_setprio(1); NMFMA; __builtin_amdgcn_s_setprio(0); \
    if (pf)               { asm volatile("s_waitcnt vmcnt(6)" ::: "memory"); phase_bar(); } \
    else if (kt + 1 < NKT){ asm volatile("s_waitcnt vmcnt(0)" ::: "memory"); phase_bar(); } \
    kt++; \
}

    f32x4 acc[4][4] = {};
    const int NKT = K >> 6;

    // prologue: 2-deep prefetch (tiles 0,1), then publish tile 0
    NSTG6(0); NADV;
    NSTG6(1); NADV;
    asm volatile("s_waitcnt vmcnt(6)" ::: "memory");
    phase_bar();

    int kt = 0;
    bf16x8 bfv[4], afv[4];
    #pragma unroll 1
    for (int kt3 = 0; kt3 < NKT; kt3 += 3) {
        NITER(0, 2);
        NITER(1, 0);
        NITER(2, 1);
    }

    float4 bv4[4];
    #pragma unroll
    for (int ni = 0; ni < 4; ni++)
        bv4[ni] = *(const float4*)&bias[n0 + wc * 64 + ni * 16 + quad * 4];

    #pragma unroll
    for (int mi = 0; mi < 4; mi++) {
        const int m = m0 + wr * 64 + mi * 16 + l16;
        #pragma unroll
        for (int ni = 0; ni < 4; ni++) {
            const int nb2 = n0 + wc * 64 + ni * 16 + quad * 4;
            float* xp = &x[(size_t)m * N + nb2];
            float4 xo = *(float4*)xp;
            xo.x += acc[mi][ni][0] + bv4[ni].x;
            xo.y += acc[mi][ni][1] + bv4[ni].y;
            xo.z += acc[mi][ni][2] + bv4[ni].z;
            xo.w += acc[mi][ni][3] + bv4[ni].w;
            *(float4*)xp = xo;      // one writer per element: no race
        }
    }
#undef NSTG_A
#undef NSTG_B
#undef NSTG6
#undef NADV
#undef NLD
#undef NMFMA
#undef NITER
}

// ---------------- MFMA flash attention: 128 queries/block ----------------
// grid (qt=4, h=12, b=16); block 256 = 4 waves; wave w owns queries w*32..w*32+31 (2 chunks of 16).
// Q-fragments loaded direct from global (no Ql LDS); K/V staged once per 128-key stage, feeds 2 chunks.
__global__ __launch_bounds__(256) void attn_k(const bf16* __restrict__ qkv, const int* __restrict__ mask,
                                              bf16* __restrict__ y)
{
    const int qt = blockIdx.x, h = blockIdx.y, b = blockIdx.z;
    const int qbase = qt * 128, tokb = b * 512;
    __shared__ __align__(16) unsigned short Kl[128][72];
    __shared__ __align__(16) unsigned short Vt[64][136];
    __shared__ __align__(16) unsigned short Ptq[4][16][136];
    __shared__ float mkf[128];

    const int tid = threadIdx.x, wave = tid >> 6, lane = tid & 63;
    const int quad = lane >> 4, l16 = lane & 15;

    // Q fragments for both chunks, direct from global (L2-resident)
    bf16x8 bq[2][2];
    #pragma unroll
    for (int qc = 0; qc < 2; qc++) {
        const bf16* qp = &qkv[(size_t)(tokb + qbase + wave * 32 + qc * 16 + l16) * 2304 + h * 64];
        bq[qc][0] = __builtin_bit_cast(bf16x8, *(const uint4*)(qp + quad * 8));
        bq[qc][1] = __builtin_bit_cast(bf16x8, *(const uint4*)(qp + 32 + quad * 8));
    }

    float m_i[2] = { -INFINITY, -INFINITY }, l_i[2] = { 0.f, 0.f };
    f32x4 Oacc[2][4] = {};

    const int nst = qt + 1;
    for (int s = 0; s < nst; s++) {
        const int j0 = s * 128;
        __syncthreads();    // WAR: Kl/Vt/Ptq from previous stage
        {   // stage K row-major, V transposed, pad-mask as additive -inf
            int key = tid >> 1, c0 = (tid & 1) * 32;
            const bf16* kg = &qkv[(size_t)(tokb + j0 + key) * 2304 + 768  + h * 64 + c0];
            const bf16* vg = &qkv[(size_t)(tokb + j0 + key) * 2304 + 1536 + h * 64 + c0];
            #pragma unroll
            for (int q = 0; q < 4; q++)
                *(uint4*)&Kl[key][c0 + q * 8] = *(const uint4*)(kg + q * 8);
            union { uint4 u[4]; unsigned short e[32]; } vv;
            #pragma unroll
            for (int q = 0; q < 4; q++) vv.u[q] = *(const uint4*)(vg + q * 8);
            #pragma unroll
            for (int j = 0; j < 32; j++) Vt[c0 + j][key] = vv.e[j];
            if (tid < 128) mkf[tid] = mask[b * 512 + j0 + tid] ? 0.f : -INFINITY;
        }
        __syncthreads();

        #pragma unroll
        for (int qc = 0; qc < 2; qc++) {
            const int qi = qbase + wave * 32 + qc * 16 + l16;

            // S^T = K · Q^T
            f32x4 sc[8] = {};
            #pragma unroll
            for (int kcc = 0; kcc < 8; kcc++) {
                bf16x8 af0 = __builtin_bit_cast(bf16x8, *(const uint4*)&Kl[kcc * 16 + l16][quad * 8]);
                bf16x8 af1 = __builtin_bit_cast(bf16x8, *(const uint4*)&Kl[kcc * 16 + l16][32 + quad * 8]);
                sc[kcc] = __builtin_amdgcn_mfma_f32_16x16x32_bf16(af0, bq[qc][0], sc[kcc], 0, 0, 0);
                sc[kcc] = __builtin_amdgcn_mfma_f32_16x16x32_bf16(af1, bq[qc][1], sc[kcc], 0, 0, 0);
            }

            float pv[8][4];
            float mx = -INFINITY;
            #pragma unroll
            for (int kcc = 0; kcc < 8; kcc++) {
                float4 mk4 = *(const float4*)&mkf[kcc * 16 + quad * 4];
                float mkr[4] = { mk4.x, mk4.y, mk4.z, mk4.w };
                #pragma unroll
                for (int r = 0; r < 4; r++) {
                    int krel = kcc * 16 + quad * 4 + r;
                    float sval = (j0 + krel <= qi) ? (sc[kcc][r] * 0.125f + mkr[r]) : -INFINITY;
                    pv[kcc][r] = sval;
                    mx = fmaxf(mx, sval);
                }
            }
            mx = fmaxf(mx, __shfl_xor(mx, 16, 64));
            mx = fmaxf(mx, __shfl_xor(mx, 32, 64));
            float mn = fmaxf(m_i[qc], mx);
            float alpha = (mn == -INFINITY) ? 1.f : __expf(m_i[qc] - mn);
            float lsum = 0.f;
            #pragma unroll
            for (int kcc = 0; kcc < 8; kcc++)
                #pragma unroll
                for (int r = 0; r < 4; r++) {
                    float pp = (pv[kcc][r] == -INFINITY) ? 0.f : __expf(pv[kcc][r] - mn);
                    pv[kcc][r] = pp; lsum += pp;
                }
            lsum += __shfl_xor(lsum, 16, 64);
            lsum += __shfl_xor(lsum, 32, 64);
            m_i[qc] = mn; l_i[qc] = alpha * l_i[qc] + lsum;

            #pragma unroll
            for (int kcc = 0; kcc < 8; kcc++)
                *(uint2*)&Ptq[wave][l16][kcc * 16 + quad * 4] = pack4bf(pv[kcc]);
            #pragma unroll
            for (int mc = 0; mc < 4; mc++)
                #pragma unroll
                for (int r = 0; r < 4; r++) Oacc[qc][mc][r] *= alpha;

            __syncthreads();   // uniform across waves (same qc sequence)

            #pragma unroll
            for (int kcc = 0; kcc < 4; kcc++) {
                bf16x8 pb = __builtin_bit_cast(bf16x8, *(const uint4*)&Ptq[wave][l16][kcc * 32 + quad * 8]);
                #pragma unroll
                for (int mc = 0; mc < 4; mc++) {
                    bf16x8 vf = __builtin_bit_cast(bf16x8, *(const uint4*)&Vt[mc * 16 + l16][kcc * 32 + quad * 8]);
                    Oacc[qc][mc] = __builtin_amdgcn_mfma_f32_16x16x32_bf16(vf, pb, Oacc[qc][mc], 0, 0, 0);
                }
            }
        }
    }

    #pragma unroll
    for (int qc = 0; qc < 2; qc++) {
        float inv = (l_i[qc] > 0.f) ? 1.f / l_i[qc] : 0.f;   // fully-masked row -> 0
        const int tok = tokb + qbase + wave * 32 + qc * 16 + l16;
        #pragma unroll
        for (int mc = 0; mc < 4; mc++) {
            float v[4] = { Oacc[qc][mc][0] * inv, Oacc[qc][mc][1] * inv,
                           Oacc[qc][mc][2] * inv, Oacc[qc][mc][3] * inv };
            *(uint2*)&y[(size_t)tok * 768 + h * 64 + mc * 16 + quad * 4] = pack4bf(v);
        }
    }
}

// ---------------- final LN + last-token select + head (fp32) ----------------
__global__ __launch_bounds__(256) void head_k(const float* __restrict__ x, const int* __restrict__ lastidx,
                                              const float* __restrict__ ls, const float* __restrict__ lb,
                                              const float* __restrict__ hw, const float* __restrict__ hb,
                                              float* __restrict__ out)
{
    int b = blockIdx.x, tid = threadIdx.x;
    const float* xr = x + ((size_t)(b * 512 + lastidx[b])) * 768;
    float v0 = xr[tid], v1 = xr[tid + 256], v2 = xr[tid + 512];
    __shared__ float rs[256], rq[256];
    rs[tid] = v0 + v1 + v2; rq[tid] = v0 * v0 + v1 * v1 + v2 * v2;
    __syncthreads();
    for (int st = 128; st > 0; st >>= 1) {
        if (tid < st) { rs[tid] += rs[tid + st]; rq[tid] += rq[tid + st]; }
        __syncthreads();
    }
    float mean = rs[0] * (1.f / 768.f);
    float var  = rq[0] * (1.f / 768.f) - mean * mean;
    float rstd = rsqrtf(var + 1e-5f);
    float part[9];
    #pragma unroll
    for (int a = 0; a < 9; a++) part[a] = 0.f;
    float vv[3] = { v0, v1, v2 };
    #pragma unroll
    for (int e = 0; e < 3; e++) {
        int d = tid + e * 256;
        float xnv = (vv[e] - mean) * rstd * ls[d] + lb[d];
        #pragma unroll
        for (int a = 0; a < 9; a++) part[a] += xnv * hw[d * 9 + a];
    }
    __shared__ float r9[9][256];
    #pragma unroll
    for (int a = 0; a < 9; a++) r9[a][tid] = part[a];
    __syncthreads();
    for (int st = 128; st > 0; st >>= 1) {
        if (tid < st) {
            for (int a = 0; a < 9; a++) r9[a][tid] += r9[a][tid + st];
        }
        __syncthreads();
    }
    if (tid < 9) out[b * 9 + tid] = r9[tid][0] + hb[tid];
}

extern "C" void kernel_launch(void* const* d_in, const int* in_sizes, int n_in,
                              void* d_out, int out_size, void* d_ws, size_t ws_size,
                              hipStream_t stream) {
    const int*   cards   = (const int*)  d_in[0];
    const int*   players = (const int*)  d_in[1];
    const int*   deck    = (const int*)  d_in[2];
    const int*   oppd    = (const int*)  d_in[3];
    const float* tok     = (const float*)d_in[4];
    const float* pemb    = (const float*)d_in[5];
    const float* pos     = (const float*)d_in[6];
    const float* ln1s  = (const float*)d_in[9];
    const float* ln1b  = (const float*)d_in[10];
    const float* qkvw  = (const float*)d_in[11];
    const float* qkvb  = (const float*)d_in[12];
    const float* projw = (const float*)d_in[13];
    const float* projb = (const float*)d_in[14];
    const float* ln2s  = (const float*)d_in[15];
    const float* ln2b  = (const float*)d_in[16];
    const float* fc1w  = (const float*)d_in[17];
    const float* fc1b  = (const float*)d_in[18];
    const float* fc2w  = (const float*)d_in[19];
    const float* fc2b  = (const float*)d_in[20];
    const float* lnfs  = (const float*)d_in[21];
    const float* lnfb  = (const float*)d_in[22];
    const float* hw    = (const float*)d_in[23];
    const float* hb    = (const float*)d_in[24];
    float* out = (float*)d_out;

    char* p = (char*)d_ws;
    auto alloc = [&](size_t bytes) { char* q = p; p += (bytes + 255) & ~((size_t)255); return q; };
    float* x     = (float*)alloc(8192ull * 768 * 4);
    bf16*  xn    = (bf16*) alloc(8192ull * 768 * 2);
    bf16*  big   = (bf16*) alloc(8192ull * 3072 * 2);
    bf16*  wt    = (bf16*) alloc(7077888ull * 2);      // all 4 transposed mats of one layer
    float* deckm = (float*)alloc(2ull * 16 * 768 * 4);
    int*   maskb = (int*)  alloc(8192ull * 4);
    int*   lasti = (int*)  alloc(64);

    bf16* wq = wt;                        // [2304][768]
    bf16* wp = wq + 2304ull * 768;        // [768][768]
    bf16* w1 = wp + 768ull * 768;         // [3072][768]
    bf16* w2 = w1 + 3072ull * 768;        // [768][3072]

    deckmean_k<<<dim3(16, 2), 256, 0, stream>>>(deck, oppd, tok, deckm);
    mask_k<<<16, 512, 0, stream>>>(cards, maskb, lasti);
    embed_k<<<8192, 256, 0, stream>>>(cards, players, tok, pemb, pos, deckm, x);

    for (int i = 0; i < 6; i++) {
        transpose4_k<<<1728, 256, 0, stream>>>(
            qkvw + (size_t)i * 768 * 2304, projw + (size_t)i * 768 * 768,
            fc1w + (size_t)i * 768 * 3072, fc2w + (size_t)i * 3072 * 768,
            wq, wp, w1, w2);

        // attention block
        ln_k<<<8192, 192, 0, stream>>>(x, ln1s + i * 768, ln1b + i * 768, xn);
        gemm256_k<<<288, 512, 0, stream>>>(xn, wq, qkvb + i * 2304, big, 2304, 768, 0, 9);
        attn_k<<<dim3(4, 12, 16), 256, 0, stream>>>(big, maskb, xn);
        gemmn128_k<<<192, 512, 0, stream>>>(xn, wp, projb + i * 768, x, 768, 768, 6);
        // MLP block
        ln_k<<<8192, 192, 0, stream>>>(x, ln2s + i * 768, ln2b + i * 768, xn);
        gemm256_k<<<384, 512, 0, stream>>>(xn, w1, fc1b + i * 3072, big, 3072, 768, 1, 12);
        gemmn128_k<<<192, 512, 0, stream>>>(big, w2, fc2b + i * 768, x, 768, 3072, 6);
    }

    head_k<<<16, 256, 0, stream>>>(x, lasti, lnfs, lnfb, hw, hb, out);
}

// Round 4
// 1920.488 us; speedup vs baseline: 1.0393x; 1.0393x over previous
//
#include <hip/hip_runtime.h>
#include <hip/hip_bf16.h>
#include <math.h>

typedef __hip_bfloat16 bf16;
typedef __bf16 bf16x8 __attribute__((ext_vector_type(8)));
typedef float f32x4 __attribute__((ext_vector_type(4)));

__device__ __forceinline__ float b2f(bf16 v){ return __bfloat162float(v); }
__device__ __forceinline__ bf16  f2b(float v){ return __float2bfloat16(v); }

// tanh-form gelu (~6 VALU ops); max |diff vs erf-gelu| ~1e-3
__device__ __forceinline__ float gelu_f(float v){
    float y = v * (1.f + 0.044715f * v * v);
    return v / (1.f + __expf(-1.5957691216057308f * y));
}

// async global->LDS, 16B per lane; LDS dest = wave-uniform base + lane*16
__device__ __forceinline__ void gl_lds16(const bf16* g, bf16* l) {
    __builtin_amdgcn_global_load_lds((const __attribute__((address_space(1))) unsigned int*)g,
                                     (__attribute__((address_space(3))) unsigned int*)l, 16, 0, 0);
}

__device__ __forceinline__ uint2 pack4bf(const float* v){
    union { unsigned short e[4]; uint2 u; } pk;
    #pragma unroll
    for (int r = 0; r < 4; r++) pk.e[r] = __builtin_bit_cast(unsigned short, f2b(v[r]));
    return pk.u;
}

// raw barrier without the compiler's vmcnt(0) drain; sched fences pin phase structure
__device__ __forceinline__ void phase_bar() {
    __builtin_amdgcn_sched_barrier(0);
    __builtin_amdgcn_s_barrier();
    __builtin_amdgcn_sched_barrier(0);
}

// ---------------- deck means ----------------
__global__ __launch_bounds__(256) void deckmean_k(const int* __restrict__ deck, const int* __restrict__ opp,
                                                  const float* __restrict__ tok, float* __restrict__ deckm)
{
    int b = blockIdx.x, w = blockIdx.y;
    const int* dk = (w ? opp : deck) + b * 8;
    int idx[8];
    #pragma unroll
    for (int j = 0; j < 8; j++) idx[j] = dk[j];
    float* out = deckm + (size_t)(w * 16 + b) * 768;
    for (int d = threadIdx.x; d < 768; d += 256) {
        float s = 0.f;
        #pragma unroll
        for (int j = 0; j < 8; j++) s += tok[(size_t)idx[j] * 768 + d];
        out[d] = s * 0.125f;
    }
}

// ---------------- mask + last_idx ----------------
__global__ __launch_bounds__(512) void mask_k(const int* __restrict__ cards, int* __restrict__ maskb,
                                              int* __restrict__ lastidx)
{
    int b = blockIdx.x, t = threadIdx.x;
    int m = (cards[b * 512 + t] != 0) ? 1 : 0;
    maskb[b * 512 + t] = m;
    __shared__ int red[512];
    red[t] = m; __syncthreads();
    for (int st = 256; st > 0; st >>= 1) { if (t < st) red[t] += red[t + st]; __syncthreads(); }
    if (t == 0) {
        int cnt = red[0];
        if (cnt == 0) { maskb[b * 512] = 1; cnt = 1; }  // all-pad fix
        lastidx[b] = cnt - 1;
    }
}

// ---------------- embedding sum -> fp32 residual stream ----------------
__global__ __launch_bounds__(256) void embed_k(const int* __restrict__ cards, const int* __restrict__ players,
                                               const float* __restrict__ tok, const float* __restrict__ pemb,
                                               const float* __restrict__ pos, const float* __restrict__ deckm,
                                               float* __restrict__ x)
{
    int t = blockIdx.x;
    int b = t >> 9, ti = t & 511;
    int cd = cards[t];
    int p = players[t]; p = p < 0 ? 0 : (p > 1 ? 1 : p);
    const float* tr  = tok  + (size_t)cd * 768;
    const float* pr  = pemb + (size_t)p  * 768;
    const float* po  = pos  + (size_t)ti * 768;
    const float* dm = deckm + (size_t)b * 768;
    const float* om = deckm + (size_t)(16 + b) * 768;
    float* xr = x + (size_t)t * 768;
    for (int d = threadIdx.x; d < 768; d += 256)
        xr[d] = tr[d] + pr[d] + po[d] + dm[d] + om[d];
}

// ---------------- layernorm (vectorized): fp32 in -> bf16 out, 192 thr/row ----------------
__global__ __launch_bounds__(192) void ln_k(const float* __restrict__ x, const float* __restrict__ s,
                                            const float* __restrict__ b, bf16* __restrict__ out)
{
    int row = blockIdx.x, tid = threadIdx.x;
    float4 v = ((const float4*)(x + (size_t)row * 768))[tid];
    float sum = v.x + v.y + v.z + v.w;
    float sq  = v.x * v.x + v.y * v.y + v.z * v.z + v.w * v.w;
    #pragma unroll
    for (int off = 32; off > 0; off >>= 1) {
        sum += __shfl_xor(sum, off, 64);
        sq  += __shfl_xor(sq,  off, 64);
    }
    __shared__ float red[6];
    int wv = tid >> 6;
    if ((tid & 63) == 0) { red[wv] = sum; red[3 + wv] = sq; }
    __syncthreads();
    float S = red[0] + red[1] + red[2];
    float Q = red[3] + red[4] + red[5];
    float mean = S * (1.f / 768.f);
    float var  = Q * (1.f / 768.f) - mean * mean;
    float rstd = rsqrtf(var + 1e-5f);
    float4 sv = ((const float4*)s)[tid];
    float4 bv = ((const float4*)b)[tid];
    float o[4] = { (v.x - mean) * rstd * sv.x + bv.x, (v.y - mean) * rstd * sv.y + bv.y,
                   (v.z - mean) * rstd * sv.z + bv.z, (v.w - mean) * rstd * sv.w + bv.w };
    ((uint2*)(out + (size_t)row * 768))[tid] = pack4bf(o);
}

// ---------------- weight transpose+downcast: 64x64 tiles, in-register 4x4 transpose ----------------
// tiles: qkv 12x36=432, proj 12x12=144, fc1 12x48=576, fc2 48x12=576 -> 1728 blocks
__global__ __launch_bounds__(256) void transpose4_k(const float* __restrict__ qw, const float* __restrict__ pw,
                                                    const float* __restrict__ f1, const float* __restrict__ f2,
                                                    bf16* __restrict__ oq, bf16* __restrict__ op,
                                                    bf16* __restrict__ o1, bf16* __restrict__ o2)
{
    int t = blockIdx.x;
    const float* in; bf16* out; int K, N, nbx;
    if (t < 432)       { in = qw; out = oq; K = 768;  N = 2304; nbx = 36; }
    else if (t < 576)  { in = pw; out = op; K = 768;  N = 768;  t -= 432;  nbx = 12; }
    else if (t < 1152) { in = f1; out = o1; K = 768;  N = 3072; t -= 576;  nbx = 48; }
    else               { in = f2; out = o2; K = 3072; N = 768;  t -= 1152; nbx = 12; }
    int n0 = (t % nbx) * 64, k0 = (t / nbx) * 64;
    int kq = threadIdx.x & 15, nq = threadIdx.x >> 4;
    float4 rr[4];
    #pragma unroll
    for (int r = 0; r < 4; r++)
        rr[r] = *(const float4*)&in[(size_t)(k0 + kq * 4 + r) * N + n0 + nq * 4];
    const float* fp = (const float*)rr;
    #pragma unroll
    for (int c = 0; c < 4; c++) {
        float v[4] = { fp[c], fp[4 + c], fp[8 + c], fp[12 + c] };
        *(uint2*)&out[(size_t)(n0 + nq * 4 + c) * K + k0 + kq * 4] = pack4bf(v);
    }
}

// ---------------- MFMA GEMM 256x256, 8-phase pipelined, NAMED double-buffer LDS ----------------
// 512 thr = 8 waves (2M x 4N), per-wave 128x64 output = acc[8][4].
// LDS = 4 distinct named arrays (As0/As1/Bs0/Bs1, 32KB each): compile-time buffer selection lets
// the waitcnt pass alias-check ds_read vs outstanding LDS-DMA per object -> no conservative
// vmcnt(0) drains before ds_reads (the round-0..3 serializer).
// Clean alternation: all 8 gl_lds for tile t+1 target the OTHER pair, spread across P0/P1/P2;
// one explicit boundary wait (required: cross-wave publish) at end-P3 + barrier.
__global__ __launch_bounds__(512, 2) void gemm256_k(const bf16* __restrict__ A, const bf16* __restrict__ BT,
                                                    const float* __restrict__ bias, bf16* __restrict__ out,
                                                    int N, int K, int act, int nbn)
{
    __shared__ __align__(16) bf16 As0[256 * 64];
    __shared__ __align__(16) bf16 As1[256 * 64];
    __shared__ __align__(16) bf16 Bs0[256 * 64];
    __shared__ __align__(16) bf16 Bs1[256 * 64];

    const int tid  = threadIdx.x;
    const int lane = tid & 63, wid = tid >> 6;
    const int quad = lane >> 4, l16 = lane & 15;
    const int wr = wid >> 2, wc = wid & 3;
    const int cg0 = quad ^ (l16 & 7);   // physical col-group for kk=0
    const int cg1 = cg0 ^ 4;            // physical col-group for kk=32

    const int nwg  = gridDim.x;                       // multiple of 8 for all call sites
    const int wgid = ((int)blockIdx.x & 7) * (nwg >> 3) + ((int)blockIdx.x >> 3);
    const int mt = wgid / nbn, nt = wgid - mt * nbn;
    const int m0 = mt * 256, n0 = nt * 256;

    // per-thread staging source: sweep s covers tile rows s*64..s*64+63; each wave 8 rows/sweep
    const int srow = wid * 8 + (lane >> 3);
    const int scg  = (lane & 7) ^ (lane >> 3);        // pre-swizzled global col-group
    const bf16* sa[4]; const bf16* sb[4];
    #pragma unroll
    for (int s = 0; s < 4; s++) {
        sa[s] = A  + (size_t)(m0 + s * 64 + srow) * K + scg * 8;
        sb[s] = BT + (size_t)(n0 + s * 64 + srow) * K + scg * 8;
    }

#define STG_A2(s, DST) gl_lds16(sa[s], &DST[((s) * 64 + wid * 8) * 64])
#define STG_B2(s, DST) gl_lds16(sb[s], &DST[((s) * 64 + wid * 8) * 64])
#define ADV { _Pragma("unroll") for (int s = 0; s < 4; s++) { sa[s] += 64; sb[s] += 64; } }
#define LD_B2(BV, cg, BC) { _Pragma("unroll") for (int ni = 0; ni < 4; ni++) \
    BV[ni] = __builtin_bit_cast(bf16x8, *(const uint4*)&BC[(wc * 64 + ni * 16 + l16) * 64 + (cg) * 8]); }
#define LD_A2(rb, cg, AC) { _Pragma("unroll") for (int mi = 0; mi < 4; mi++) \
    afv[mi] = __builtin_bit_cast(bf16x8, *(const uint4*)&AC[(wr * 128 + (rb) + mi * 16 + l16) * 64 + (cg) * 8]); }
#define MFMA16(MB, BV) { _Pragma("unroll") for (int mi = 0; mi < 4; mi++) \
    _Pragma("unroll") for (int ni = 0; ni < 4; ni++) \
        acc[(MB) + mi][ni] = __builtin_amdgcn_mfma_f32_16x16x32_bf16(BV[ni], afv[mi], acc[(MB) + mi][ni], 0, 0, 0); }

// one K-tile, 4 phases; reads from (AC,BC), stages tile t+1 into (AN,BN) when PF
#define TILE256(AC, BC, AN, BN, PF) { \
    LD_B2(bfv0, cg0, BC); LD_A2(0, cg0, AC); \
    if (PF) { STG_B2(0, BN); STG_B2(1, BN); STG_B2(2, BN); STG_B2(3, BN); } \
    phase_bar(); \
    __builtin_amdgcn_s_setprio(1); MFMA16(0, bfv0); __builtin_amdgcn_s_setprio(0); \
    phase_bar(); \
    LD_B2(bfv1, cg1, BC); LD_A2(0, cg1, AC); \
    if (PF) { STG_A2(0, AN); STG_A2(2, AN); } \
    phase_bar(); \
    __builtin_amdgcn_s_setprio(1); MFMA16(0, bfv1); __builtin_amdgcn_s_setprio(0); \
    phase_bar(); \
    LD_A2(64, cg0, AC); \
    if (PF) { STG_A2(1, AN); STG_A2(3, AN); ADV; } \
    phase_bar(); \
    __builtin_amdgcn_s_setprio(1); MFMA16(4, bfv0); __builtin_amdgcn_s_setprio(0); \
    phase_bar(); \
    LD_A2(64, cg1, AC); \
    phase_bar(); \
    __builtin_amdgcn_s_setprio(1); MFMA16(4, bfv1); __builtin_amdgcn_s_setprio(0); \
    if (PF) { asm volatile("s_waitcnt vmcnt(0)" ::: "memory"); } \
    phase_bar(); }

    f32x4 acc[8][4] = {};
    const int NKT = K >> 6;   // 12 at all call sites (even)

    // prologue: stage tile 0 -> As0/Bs0
    STG_B2(0, Bs0); STG_B2(1, Bs0); STG_B2(2, Bs0); STG_B2(3, Bs0);
    STG_A2(0, As0); STG_A2(1, As0); STG_A2(2, As0); STG_A2(3, As0);
    ADV;
    asm volatile("s_waitcnt vmcnt(0)" ::: "memory");
    phase_bar();

    bf16x8 bfv0[4], bfv1[4], afv[4];
    #pragma unroll 1
    for (int kt2 = 0; kt2 < NKT; kt2 += 2) {
        { const bool pf = true;                 // kt2 <= NKT-2 -> tile kt2+1 always exists
          TILE256(As0, Bs0, As1, Bs1, pf); }
        { const bool pf = (kt2 + 2 < NKT);
          TILE256(As1, Bs1, As0, Bs0, pf); }
    }

    float4 bv[4];
    #pragma unroll
    for (int ni = 0; ni < 4; ni++)
        bv[ni] = *(const float4*)&bias[n0 + wc * 64 + ni * 16 + quad * 4];

    #pragma unroll
    for (int mi = 0; mi < 8; mi++) {
        const int m = m0 + wr * 128 + mi * 16 + l16;
        #pragma unroll
        for (int ni = 0; ni < 4; ni++) {
            const int nb2 = n0 + wc * 64 + ni * 16 + quad * 4;
            float v[4] = { acc[mi][ni][0] + bv[ni].x, acc[mi][ni][1] + bv[ni].y,
                           acc[mi][ni][2] + bv[ni].z, acc[mi][ni][3] + bv[ni].w };
            if (act) {
                #pragma unroll
                for (int r = 0; r < 4; r++) v[r] = gelu_f(v[r]);
            }
            *(uint2*)&out[(size_t)m * N + nb2] = pack4bf(v);
        }
    }
#undef STG_A2
#undef STG_B2
#undef ADV
#undef LD_B2
#undef LD_A2
#undef MFMA16
#undef TILE256
}

// ---------------- MFMA GEMM 256x128 narrow-N (proj, fc2), pipelined, NAMED triple-buffer ----------------
// 512 thr = 8 waves (4M x 2N), per-wave 64x64 output = acc[4][4]; 2 phases x 16 MFMA per K-tile.
// Six named LDS arrays (NA0-2 32KB, NB0-2 16KB = 144 KiB), 2-deep prefetch with counted vmcnt(6):
// compile-time buffer names -> waitcnt pass can prove ds_reads don't alias in-flight LDS-DMA.
// Requires NKT % 3 == 0 (call sites: K=768, 3072).
__global__ __launch_bounds__(512, 2) void gemmn128_k(const bf16* __restrict__ A, const bf16* __restrict__ BT,
                                                     const float* __restrict__ bias, float* __restrict__ x,
                                                     int N, int K, int nbn)
{
    __shared__ __align__(16) bf16 NA0[256 * 64];
    __shared__ __align__(16) bf16 NA1[256 * 64];
    __shared__ __align__(16) bf16 NA2[256 * 64];
    __shared__ __align__(16) bf16 NB0[128 * 64];
    __shared__ __align__(16) bf16 NB1[128 * 64];
    __shared__ __align__(16) bf16 NB2[128 * 64];

    const int tid  = threadIdx.x;
    const int lane = tid & 63, wid = tid >> 6;
    const int quad = lane >> 4, l16 = lane & 15;
    const int wr = wid >> 1, wc = wid & 1;
    const int cg0 = quad ^ (l16 & 7);
    const int cg1 = cg0 ^ 4;

    const int nwg  = gridDim.x;                        // multiple of 8
    const int wgid = ((int)blockIdx.x & 7) * (nwg >> 3) + ((int)blockIdx.x >> 3);
    const int mt = wgid / nbn, nt = wgid - mt * nbn;
    const int m0 = mt * 256, n0 = nt * 128;

    const int srow = wid * 8 + (lane >> 3);
    const int scg  = (lane & 7) ^ (lane >> 3);         // pre-swizzled global col-group
    const bf16* sa[4]; const bf16* sb[2];
    #pragma unroll
    for (int s = 0; s < 4; s++) sa[s] = A  + (size_t)(m0 + s * 64 + srow) * K + scg * 8;
    #pragma unroll
    for (int s = 0; s < 2; s++) sb[s] = BT + (size_t)(n0 + s * 64 + srow) * K + scg * 8;

#define NSTG6(NA, NB) { \
    gl_lds16(sa[0], &NA[(0 * 64 + wid * 8) * 64]); gl_lds16(sa[1], &NA[(1 * 64 + wid * 8) * 64]); \
    gl_lds16(sa[2], &NA[(2 * 64 + wid * 8) * 64]); gl_lds16(sa[3], &NA[(3 * 64 + wid * 8) * 64]); \
    gl_lds16(sb[0], &NB[(0 * 64 + wid * 8) * 64]); gl_lds16(sb[1], &NB[(1 * 64 + wid * 8) * 64]); }
#define NADV { _Pragma("unroll") for (int s = 0; s < 4; s++) sa[s] += 64; sb[0] += 64; sb[1] += 64; }
#define NLD(cg, NA, NB) { _Pragma("unroll") for (int i = 0; i < 4; i++) { \
    bfv[i] = __builtin_bit_cast(bf16x8, *(const uint4*)&NB[(wc * 64 + i * 16 + l16) * 64 + (cg) * 8]); \
    afv[i] = __builtin_bit_cast(bf16x8, *(const uint4*)&NA[(wr * 64 + i * 16 + l16) * 64 + (cg) * 8]); } }
#define NMFMA { _Pragma("unroll") for (int mi = 0; mi < 4; mi++) \
    _Pragma("unroll") for (int ni = 0; ni < 4; ni++) \
        acc[mi][ni] = __builtin_amdgcn_mfma_f32_16x16x32_bf16(bfv[ni], afv[mi], acc[mi][ni], 0, 0, 0); }
// one K-tile: P0 {ds_read cg0 | stage kt+2 -> (NAs,NBs)} MFMA16; P1 {ds_read cg1} MFMA16, publish kt+1
#define NITER(NAc, NBc, NAs, NBs) { \
    const bool pf = (kt + 2 < NKT); \
    NLD(cg0, NAc, NBc); \
    if (pf) { NSTG6(NAs, NBs); NADV; } \
    phase_bar(); \
    __builtin_amdgcn_s_setprio(1); NMFMA; __builtin_amdgcn_s_setprio(0); \
    phase_bar(); \
    NLD(cg1, NAc, NBc); \
    phase_bar(); \
    __builtin_amdgcn_s_setprio(1); NMFMA; __builtin_amdgcn_s_setprio(0); \
    if (pf)               { asm volatile("s_waitcnt vmcnt(6)" ::: "memory"); phase_bar(); } \
    else if (kt + 1 < NKT){ asm volatile("s_waitcnt vmcnt(0)" ::: "memory"); phase_bar(); } \
    kt++; \
}

    f32x4 acc[4][4] = {};
    const int NKT = K >> 6;

    // prologue: 2-deep prefetch (tiles 0,1), then publish tile 0
    NSTG6(NA0, NB0); NADV;
    NSTG6(NA1, NB1); NADV;
    asm volatile("s_waitcnt vmcnt(6)" ::: "memory");
    phase_bar();

    int kt = 0;
    bf16x8 bfv[4], afv[4];
    #pragma unroll 1
    for (int kt3 = 0; kt3 < NKT; kt3 += 3) {
        NITER(NA0, NB0, NA2, NB2);
        NITER(NA1, NB1, NA0, NB0);
        NITER(NA2, NB2, NA1, NB1);
    }

    float4 bv4[4];
    #pragma unroll
    for (int ni = 0; ni < 4; ni++)
        bv4[ni] = *(const float4*)&bias[n0 + wc * 64 + ni * 16 + quad * 4];

    #pragma unroll
    for (int mi = 0; mi < 4; mi++) {
        const int m = m0 + wr * 64 + mi * 16 + l16;
        #pragma unroll
        for (int ni = 0; ni < 4; ni++) {
            const int nb2 = n0 + wc * 64 + ni * 16 + quad * 4;
            float* xp = &x[(size_t)m * N + nb2];
            float4 xo = *(float4*)xp;
            xo.x += acc[mi][ni][0] + bv4[ni].x;
            xo.y += acc[mi][ni][1] + bv4[ni].y;
            xo.z += acc[mi][ni][2] + bv4[ni].z;
            xo.w += acc[mi][ni][3] + bv4[ni].w;
            *(float4*)xp = xo;      // one writer per element: no race
        }
    }
#undef NSTG6
#undef NADV
#undef NLD
#undef NMFMA
#undef NITER
}

// ---------------- MFMA flash attention: 128 queries/block ----------------
// grid (qt=4, h=12, b=16); block 256 = 4 waves; wave w owns queries w*32..w*32+31 (2 chunks of 16).
// Q-fragments loaded direct from global (no Ql LDS); K/V staged once per 128-key stage, feeds 2 chunks.
__global__ __launch_bounds__(256) void attn_k(const bf16* __restrict__ qkv, const int* __restrict__ mask,
                                              bf16* __restrict__ y)
{
    const int qt = blockIdx.x, h = blockIdx.y, b = blockIdx.z;
    const int qbase = qt * 128, tokb = b * 512;
    __shared__ __align__(16) unsigned short Kl[128][72];
    __shared__ __align__(16) unsigned short Vt[64][136];
    __shared__ __align__(16) unsigned short Ptq[4][16][136];
    __shared__ float mkf[128];

    const int tid = threadIdx.x, wave = tid >> 6, lane = tid & 63;
    const int quad = lane >> 4, l16 = lane & 15;

    // Q fragments for both chunks, direct from global (L2-resident)
    bf16x8 bq[2][2];
    #pragma unroll
    for (int qc = 0; qc < 2; qc++) {
        const bf16* qp = &qkv[(size_t)(tokb + qbase + wave * 32 + qc * 16 + l16) * 2304 + h * 64];
        bq[qc][0] = __builtin_bit_cast(bf16x8, *(const uint4*)(qp + quad * 8));
        bq[qc][1] = __builtin_bit_cast(bf16x8, *(const uint4*)(qp + 32 + quad * 8));
    }

    float m_i[2] = { -INFINITY, -INFINITY }, l_i[2] = { 0.f, 0.f };
    f32x4 Oacc[2][4] = {};

    const int nst = qt + 1;
    for (int s = 0; s < nst; s++) {
        const int j0 = s * 128;
        __syncthreads();    // WAR: Kl/Vt/Ptq from previous stage
        {   // stage K row-major, V transposed, pad-mask as additive -inf
            int key = tid >> 1, c0 = (tid & 1) * 32;
            const bf16* kg = &qkv[(size_t)(tokb + j0 + key) * 2304 + 768  + h * 64 + c0];
            const bf16* vg = &qkv[(size_t)(tokb + j0 + key) * 2304 + 1536 + h * 64 + c0];
            #pragma unroll
            for (int q = 0; q < 4; q++)
                *(uint4*)&Kl[key][c0 + q * 8] = *(const uint4*)(kg + q * 8);
            union { uint4 u[4]; unsigned short e[32]; } vv;
            #pragma unroll
            for (int q = 0; q < 4; q++) vv.u[q] = *(const uint4*)(vg + q * 8);
            #pragma unroll
            for (int j = 0; j < 32; j++) Vt[c0 + j][key] = vv.e[j];
            if (tid < 128) mkf[tid] = mask[b * 512 + j0 + tid] ? 0.f : -INFINITY;
        }
        __syncthreads();

        #pragma unroll
        for (int qc = 0; qc < 2; qc++) {
            const int qi = qbase + wave * 32 + qc * 16 + l16;

            // S^T = K · Q^T
            f32x4 sc[8] = {};
            #pragma unroll
            for (int kcc = 0; kcc < 8; kcc++) {
                bf16x8 af0 = __builtin_bit_cast(bf16x8, *(const uint4*)&Kl[kcc * 16 + l16][quad * 8]);
                bf16x8 af1 = __builtin_bit_cast(bf16x8, *(const uint4*)&Kl[kcc * 16 + l16][32 + quad * 8]);
                sc[kcc] = __builtin_amdgcn_mfma_f32_16x16x32_bf16(af0, bq[qc][0], sc[kcc], 0, 0, 0);
                sc[kcc] = __builtin_amdgcn_mfma_f32_16x16x32_bf16(af1, bq[qc][1], sc[kcc], 0, 0, 0);
            }

            float pv[8][4];
            float mx = -INFINITY;
            #pragma unroll
            for (int kcc = 0; kcc < 8; kcc++) {
                float4 mk4 = *(const float4*)&mkf[kcc * 16 + quad * 4];
                float mkr[4] = { mk4.x, mk4.y, mk4.z, mk4.w };
                #pragma unroll
                for (int r = 0; r < 4; r++) {
                    int krel = kcc * 16 + quad * 4 + r;
                    float sval = (j0 + krel <= qi) ? (sc[kcc][r] * 0.125f + mkr[r]) : -INFINITY;
                    pv[kcc][r] = sval;
                    mx = fmaxf(mx, sval);
                }
            }
            mx = fmaxf(mx, __shfl_xor(mx, 16, 64));
            mx = fmaxf(mx, __shfl_xor(mx, 32, 64));
            float mn = fmaxf(m_i[qc], mx);
            float alpha = (mn == -INFINITY) ? 1.f : __expf(m_i[qc] - mn);
            float lsum = 0.f;
            #pragma unroll
            for (int kcc = 0; kcc < 8; kcc++)
                #pragma unroll
                for (int r = 0; r < 4; r++) {
                    float pp = (pv[kcc][r] == -INFINITY) ? 0.f : __expf(pv[kcc][r] - mn);
                    pv[kcc][r] = pp; lsum += pp;
                }
            lsum += __shfl_xor(lsum, 16, 64);
            lsum += __shfl_xor(lsum, 32, 64);
            m_i[qc] = mn; l_i[qc] = alpha * l_i[qc] + lsum;

            #pragma unroll
            for (int kcc = 0; kcc < 8; kcc++)
                *(uint2*)&Ptq[wave][l16][kcc * 16 + quad * 4] = pack4bf(pv[kcc]);
            #pragma unroll
            for (int mc = 0; mc < 4; mc++)
                #pragma unroll
                for (int r = 0; r < 4; r++) Oacc[qc][mc][r] *= alpha;

            __syncthreads();   // uniform across waves (same qc sequence)

            #pragma unroll
            for (int kcc = 0; kcc < 4; kcc++) {
                bf16x8 pb = __builtin_bit_cast(bf16x8, *(const uint4*)&Ptq[wave][l16][kcc * 32 + quad * 8]);
                #pragma unroll
                for (int mc = 0; mc < 4; mc++) {
                    bf16x8 vf = __builtin_bit_cast(bf16x8, *(const uint4*)&Vt[mc * 16 + l16][kcc * 32 + quad * 8]);
                    Oacc[qc][mc] = __builtin_amdgcn_mfma_f32_16x16x32_bf16(vf, pb, Oacc[qc][mc], 0, 0, 0);
                }
            }
        }
    }

    #pragma unroll
    for (int qc = 0; qc < 2; qc++) {
        float inv = (l_i[qc] > 0.f) ? 1.f / l_i[qc] : 0.f;   // fully-masked row -> 0
        const int tok = tokb + qbase + wave * 32 + qc * 16 + l16;
        #pragma unroll
        for (int mc = 0; mc < 4; mc++) {
            float v[4] = { Oacc[qc][mc][0] * inv, Oacc[qc][mc][1] * inv,
                           Oacc[qc][mc][2] * inv, Oacc[qc][mc][3] * inv };
            *(uint2*)&y[(size_t)tok * 768 + h * 64 + mc * 16 + quad * 4] = pack4bf(v);
        }
    }
}

// ---------------- final LN + last-token select + head (fp32) ----------------
__global__ __launch_bounds__(256) void head_k(const float* __restrict__ x, const int* __restrict__ lastidx,
                                              const float* __restrict__ ls, const float* __restrict__ lb,
                                              const float* __restrict__ hw, const float* __restrict__ hb,
                                              float* __restrict__ out)
{
    int b = blockIdx.x, tid = threadIdx.x;
    const float* xr = x + ((size_t)(b * 512 + lastidx[b])) * 768;
    float v0 = xr[tid], v1 = xr[tid + 256], v2 = xr[tid + 512];
    __shared__ float rs[256], rq[256];
    rs[tid] = v0 + v1 + v2; rq[tid] = v0 * v0 + v1 * v1 + v2 * v2;
    __syncthreads();
    for (int st = 128; st > 0; st >>= 1) {
        if (tid < st) { rs[tid] += rs[tid + st]; rq[tid] += rq[tid + st]; }
        __syncthreads();
    }
    float mean = rs[0] * (1.f / 768.f);
    float var  = rq[0] * (1.f / 768.f) - mean * mean;
    float rstd = rsqrtf(var + 1e-5f);
    float part[9];
    #pragma unroll
    for (int a = 0; a < 9; a++) part[a] = 0.f;
    float vv[3] = { v0, v1, v2 };
    #pragma unroll
    for (int e = 0; e < 3; e++) {
        int d = tid + e * 256;
        float xnv = (vv[e] - mean) * rstd * ls[d] + lb[d];
        #pragma unroll
        for (int a = 0; a < 9; a++) part[a] += xnv * hw[d * 9 + a];
    }
    __shared__ float r9[9][256];
    #pragma unroll
    for (int a = 0; a < 9; a++) r9[a][tid] = part[a];
    __syncthreads();
    for (int st = 128; st > 0; st >>= 1) {
        if (tid < st) {
            for (int a = 0; a < 9; a++) r9[a][tid] += r9[a][tid + st];
        }
        __syncthreads();
    }
    if (tid < 9) out[b * 9 + tid] = r9[tid][0] + hb[tid];
}

extern "C" void kernel_launch(void* const* d_in, const int* in_sizes, int n_in,
                              void* d_out, int out_size, void* d_ws, size_t ws_size,
                              hipStream_t stream) {
    const int*   cards   = (const int*)  d_in[0];
    const int*   players = (const int*)  d_in[1];
    const int*   deck    = (const int*)  d_in[2];
    const int*   oppd    = (const int*)  d_in[3];
    const float* tok     = (const float*)d_in[4];
    const float* pemb    = (const float*)d_in[5];
    const float* pos     = (const float*)d_in[6];
    const float* ln1s  = (const float*)d_in[9];
    const float* ln1b  = (const float*)d_in[10];
    const float* qkvw  = (const float*)d_in[11];
    const float* qkvb  = (const float*)d_in[12];
    const float* projw = (const float*)d_in[13];
    const float* projb = (const float*)d_in[14];
    const float* ln2s  = (const float*)d_in[15];
    const float* ln2b  = (const float*)d_in[16];
    const float* fc1w  = (const float*)d_in[17];
    const float* fc1b  = (const float*)d_in[18];
    const float* fc2w  = (const float*)d_in[19];
    const float* fc2b  = (const float*)d_in[20];
    const float* lnfs  = (const float*)d_in[21];
    const float* lnfb  = (const float*)d_in[22];
    const float* hw    = (const float*)d_in[23];
    const float* hb    = (const float*)d_in[24];
    float* out = (float*)d_out;

    char* p = (char*)d_ws;
    auto alloc = [&](size_t bytes) { char* q = p; p += (bytes + 255) & ~((size_t)255); return q; };
    float* x     = (float*)alloc(8192ull * 768 * 4);
    bf16*  xn    = (bf16*) alloc(8192ull * 768 * 2);
    bf16*  big   = (bf16*) alloc(8192ull * 3072 * 2);
    bf16*  wt    = (bf16*) alloc(7077888ull * 2);      // all 4 transposed mats of one layer
    float* deckm = (float*)alloc(2ull * 16 * 768 * 4);
    int*   maskb = (int*)  alloc(8192ull * 4);
    int*   lasti = (int*)  alloc(64);

    bf16* wq = wt;                        // [2304][768]
    bf16* wp = wq + 2304ull * 768;        // [768][768]
    bf16* w1 = wp + 768ull * 768;         // [3072][768]
    bf16* w2 = w1 + 3072ull * 768;        // [768][3072]

    deckmean_k<<<dim3(16, 2), 256, 0, stream>>>(deck, oppd, tok, deckm);
    mask_k<<<16, 512, 0, stream>>>(cards, maskb, lasti);
    embed_k<<<8192, 256, 0, stream>>>(cards, players, tok, pemb, pos, deckm, x);

    for (int i = 0; i < 6; i++) {
        transpose4_k<<<1728, 256, 0, stream>>>(
            qkvw + (size_t)i * 768 * 2304, projw + (size_t)i * 768 * 768,
            fc1w + (size_t)i * 768 * 3072, fc2w + (size_t)i * 3072 * 768,
            wq, wp, w1, w2);

        // attention block
        ln_k<<<8192, 192, 0, stream>>>(x, ln1s + i * 768, ln1b + i * 768, xn);
        gemm256_k<<<288, 512, 0, stream>>>(xn, wq, qkvb + i * 2304, big, 2304, 768, 0, 9);
        attn_k<<<dim3(4, 12, 16), 256, 0, stream>>>(big, maskb, xn);
        gemmn128_k<<<192, 512, 0, stream>>>(xn, wp, projb + i * 768, x, 768, 768, 6);
        // MLP block
        ln_k<<<8192, 192, 0, stream>>>(x, ln2s + i * 768, ln2b + i * 768, xn);
        gemm256_k<<<384, 512, 0, stream>>>(xn, w1, fc1b + i * 3072, big, 3072, 768, 1, 12);
        gemmn128_k<<<192, 512, 0, stream>>>(big, w2, fc2b + i * 768, x, 768, 3072, 6);
    }

    head_k<<<16, 256, 0, stream>>>(x, lasti, lnfs, lnfb, hw, hb, out);
}

// Round 5
// 1910.470 us; speedup vs baseline: 1.0447x; 1.0052x over previous
//
#include <hip/hip_runtime.h>
#include <hip/hip_bf16.h>
#include <math.h>

typedef __hip_bfloat16 bf16;
typedef __bf16 bf16x8 __attribute__((ext_vector_type(8)));
typedef float f32x4 __attribute__((ext_vector_type(4)));

__device__ __forceinline__ float b2f(bf16 v){ return __bfloat162float(v); }
__device__ __forceinline__ bf16  f2b(float v){ return __float2bfloat16(v); }

// tanh-form gelu (~6 VALU ops); max |diff vs erf-gelu| ~1e-3
__device__ __forceinline__ float gelu_f(float v){
    float y = v * (1.f + 0.044715f * v * v);
    return v / (1.f + __expf(-1.5957691216057308f * y));
}

// async global->LDS, 16B per lane; LDS dest = wave-uniform base + lane*16
__device__ __forceinline__ void gl_lds16(const bf16* g, bf16* l) {
    __builtin_amdgcn_global_load_lds((const __attribute__((address_space(1))) unsigned int*)g,
                                     (__attribute__((address_space(3))) unsigned int*)l, 16, 0, 0);
}

__device__ __forceinline__ uint2 pack4bf(const float* v){
    union { unsigned short e[4]; uint2 u; } pk;
    #pragma unroll
    for (int r = 0; r < 4; r++) pk.e[r] = __builtin_bit_cast(unsigned short, f2b(v[r]));
    return pk.u;
}

// raw barrier without the compiler's vmcnt(0) drain; sched fences pin phase structure
__device__ __forceinline__ void phase_bar() {
    __builtin_amdgcn_sched_barrier(0);
    __builtin_amdgcn_s_barrier();
    __builtin_amdgcn_sched_barrier(0);
}

// ---------------- deck means ----------------
__global__ __launch_bounds__(256) void deckmean_k(const int* __restrict__ deck, const int* __restrict__ opp,
                                                  const float* __restrict__ tok, float* __restrict__ deckm)
{
    int b = blockIdx.x, w = blockIdx.y;
    const int* dk = (w ? opp : deck) + b * 8;
    int idx[8];
    #pragma unroll
    for (int j = 0; j < 8; j++) idx[j] = dk[j];
    float* out = deckm + (size_t)(w * 16 + b) * 768;
    for (int d = threadIdx.x; d < 768; d += 256) {
        float s = 0.f;
        #pragma unroll
        for (int j = 0; j < 8; j++) s += tok[(size_t)idx[j] * 768 + d];
        out[d] = s * 0.125f;
    }
}

// ---------------- mask + last_idx ----------------
__global__ __launch_bounds__(512) void mask_k(const int* __restrict__ cards, int* __restrict__ maskb,
                                              int* __restrict__ lastidx)
{
    int b = blockIdx.x, t = threadIdx.x;
    int m = (cards[b * 512 + t] != 0) ? 1 : 0;
    maskb[b * 512 + t] = m;
    __shared__ int red[512];
    red[t] = m; __syncthreads();
    for (int st = 256; st > 0; st >>= 1) { if (t < st) red[t] += red[t + st]; __syncthreads(); }
    if (t == 0) {
        int cnt = red[0];
        if (cnt == 0) { maskb[b * 512] = 1; cnt = 1; }  // all-pad fix
        lastidx[b] = cnt - 1;
    }
}

// ---------------- embedding sum -> fp32 residual stream ----------------
__global__ __launch_bounds__(256) void embed_k(const int* __restrict__ cards, const int* __restrict__ players,
                                               const float* __restrict__ tok, const float* __restrict__ pemb,
                                               const float* __restrict__ pos, const float* __restrict__ deckm,
                                               float* __restrict__ x)
{
    int t = blockIdx.x;
    int b = t >> 9, ti = t & 511;
    int cd = cards[t];
    int p = players[t]; p = p < 0 ? 0 : (p > 1 ? 1 : p);
    const float* tr  = tok  + (size_t)cd * 768;
    const float* pr  = pemb + (size_t)p  * 768;
    const float* po  = pos  + (size_t)ti * 768;
    const float* dm = deckm + (size_t)b * 768;
    const float* om = deckm + (size_t)(16 + b) * 768;
    float* xr = x + (size_t)t * 768;
    for (int d = threadIdx.x; d < 768; d += 256)
        xr[d] = tr[d] + pr[d] + po[d] + dm[d] + om[d];
}

// ---------------- layernorm (vectorized): fp32 in -> bf16 out, 192 thr/row ----------------
__global__ __launch_bounds__(192) void ln_k(const float* __restrict__ x, const float* __restrict__ s,
                                            const float* __restrict__ b, bf16* __restrict__ out)
{
    int row = blockIdx.x, tid = threadIdx.x;
    float4 v = ((const float4*)(x + (size_t)row * 768))[tid];
    float sum = v.x + v.y + v.z + v.w;
    float sq  = v.x * v.x + v.y * v.y + v.z * v.z + v.w * v.w;
    #pragma unroll
    for (int off = 32; off > 0; off >>= 1) {
        sum += __shfl_xor(sum, off, 64);
        sq  += __shfl_xor(sq,  off, 64);
    }
    __shared__ float red[6];
    int wv = tid >> 6;
    if ((tid & 63) == 0) { red[wv] = sum; red[3 + wv] = sq; }
    __syncthreads();
    float S = red[0] + red[1] + red[2];
    float Q = red[3] + red[4] + red[5];
    float mean = S * (1.f / 768.f);
    float var  = Q * (1.f / 768.f) - mean * mean;
    float rstd = rsqrtf(var + 1e-5f);
    float4 sv = ((const float4*)s)[tid];
    float4 bv = ((const float4*)b)[tid];
    float o[4] = { (v.x - mean) * rstd * sv.x + bv.x, (v.y - mean) * rstd * sv.y + bv.y,
                   (v.z - mean) * rstd * sv.z + bv.z, (v.w - mean) * rstd * sv.w + bv.w };
    ((uint2*)(out + (size_t)row * 768))[tid] = pack4bf(o);
}

// ---------------- weight transpose+downcast: 64x64 tiles, in-register 4x4 transpose ----------------
// tiles: qkv 12x36=432, proj 12x12=144, fc1 12x48=576, fc2 48x12=576 -> 1728 blocks
__global__ __launch_bounds__(256) void transpose4_k(const float* __restrict__ qw, const float* __restrict__ pw,
                                                    const float* __restrict__ f1, const float* __restrict__ f2,
                                                    bf16* __restrict__ oq, bf16* __restrict__ op,
                                                    bf16* __restrict__ o1, bf16* __restrict__ o2)
{
    int t = blockIdx.x;
    const float* in; bf16* out; int K, N, nbx;
    if (t < 432)       { in = qw; out = oq; K = 768;  N = 2304; nbx = 36; }
    else if (t < 576)  { in = pw; out = op; K = 768;  N = 768;  t -= 432;  nbx = 12; }
    else if (t < 1152) { in = f1; out = o1; K = 768;  N = 3072; t -= 576;  nbx = 48; }
    else               { in = f2; out = o2; K = 3072; N = 768;  t -= 1152; nbx = 12; }
    int n0 = (t % nbx) * 64, k0 = (t / nbx) * 64;
    int kq = threadIdx.x & 15, nq = threadIdx.x >> 4;
    float4 rr[4];
    #pragma unroll
    for (int r = 0; r < 4; r++)
        rr[r] = *(const float4*)&in[(size_t)(k0 + kq * 4 + r) * N + n0 + nq * 4];
    const float* fp = (const float*)rr;
    #pragma unroll
    for (int c = 0; c < 4; c++) {
        float v[4] = { fp[c], fp[4 + c], fp[8 + c], fp[12 + c] };
        *(uint2*)&out[(size_t)(n0 + nq * 4 + c) * K + k0 + kq * 4] = pack4bf(v);
    }
}

// ---------------- MFMA GEMM 256x128 (qkv, fc1): named triple-buffer + counted vmcnt, bf16 out ----------------
// Round-4's winning gemmn128 structure (named LDS objects -> alias-precise waitcnt; counted vmcnt(6),
// 2-deep prefetch), with bias + optional gelu epilogue writing bf16.
// 512 thr = 8 waves (4M x 2N), per-wave 64x64 = acc[4][4]; 2 phases x 16 MFMA per K-tile.
// Requires NKT % 3 == 0 (K=768 -> 12).
__global__ __launch_bounds__(512, 2) void gemmn128b_k(const bf16* __restrict__ A, const bf16* __restrict__ BT,
                                                      const float* __restrict__ bias, bf16* __restrict__ out,
                                                      int N, int K, int act, int nbn)
{
    __shared__ __align__(16) bf16 MA0[256 * 64];
    __shared__ __align__(16) bf16 MA1[256 * 64];
    __shared__ __align__(16) bf16 MA2[256 * 64];
    __shared__ __align__(16) bf16 MB0[128 * 64];
    __shared__ __align__(16) bf16 MB1[128 * 64];
    __shared__ __align__(16) bf16 MB2[128 * 64];

    const int tid  = threadIdx.x;
    const int lane = tid & 63, wid = tid >> 6;
    const int quad = lane >> 4, l16 = lane & 15;
    const int wr = wid >> 1, wc = wid & 1;
    const int cg0 = quad ^ (l16 & 7);
    const int cg1 = cg0 ^ 4;

    const int nwg  = gridDim.x;                        // multiple of 8
    const int wgid = ((int)blockIdx.x & 7) * (nwg >> 3) + ((int)blockIdx.x >> 3);
    const int mt = wgid / nbn, nt = wgid - mt * nbn;
    const int m0 = mt * 256, n0 = nt * 128;

    const int srow = wid * 8 + (lane >> 3);
    const int scg  = (lane & 7) ^ (lane >> 3);         // pre-swizzled global col-group
    const bf16* sa[4]; const bf16* sb[2];
    #pragma unroll
    for (int s = 0; s < 4; s++) sa[s] = A  + (size_t)(m0 + s * 64 + srow) * K + scg * 8;
    #pragma unroll
    for (int s = 0; s < 2; s++) sb[s] = BT + (size_t)(n0 + s * 64 + srow) * K + scg * 8;

#define MSTG6(NA, NB) { \
    gl_lds16(sa[0], &NA[(0 * 64 + wid * 8) * 64]); gl_lds16(sa[1], &NA[(1 * 64 + wid * 8) * 64]); \
    gl_lds16(sa[2], &NA[(2 * 64 + wid * 8) * 64]); gl_lds16(sa[3], &NA[(3 * 64 + wid * 8) * 64]); \
    gl_lds16(sb[0], &NB[(0 * 64 + wid * 8) * 64]); gl_lds16(sb[1], &NB[(1 * 64 + wid * 8) * 64]); }
#define MADV { _Pragma("unroll") for (int s = 0; s < 4; s++) sa[s] += 64; sb[0] += 64; sb[1] += 64; }
#define MLD(cg, NA, NB) { _Pragma("unroll") for (int i = 0; i < 4; i++) { \
    bfv[i] = __builtin_bit_cast(bf16x8, *(const uint4*)&NB[(wc * 64 + i * 16 + l16) * 64 + (cg) * 8]); \
    afv[i] = __builtin_bit_cast(bf16x8, *(const uint4*)&NA[(wr * 64 + i * 16 + l16) * 64 + (cg) * 8]); } }
#define MMFMA { _Pragma("unroll") for (int mi = 0; mi < 4; mi++) \
    _Pragma("unroll") for (int ni = 0; ni < 4; ni++) \
        acc[mi][ni] = __builtin_amdgcn_mfma_f32_16x16x32_bf16(bfv[ni], afv[mi], acc[mi][ni], 0, 0, 0); }
#define MITER(NAc, NBc, NAs, NBs) { \
    const bool pf = (kt + 2 < NKT); \
    MLD(cg0, NAc, NBc); \
    if (pf) { MSTG6(NAs, NBs); MADV; } \
    phase_bar(); \
    __builtin_amdgcn_s_setprio(1); MMFMA; __builtin_amdgcn_s_setprio(0); \
    phase_bar(); \
    MLD(cg1, NAc, NBc); \
    phase_bar(); \
    __builtin_amdgcn_s_setprio(1); MMFMA; __builtin_amdgcn_s_setprio(0); \
    if (pf)               { asm volatile("s_waitcnt vmcnt(6)" ::: "memory"); phase_bar(); } \
    else if (kt + 1 < NKT){ asm volatile("s_waitcnt vmcnt(0)" ::: "memory"); phase_bar(); } \
    kt++; \
}

    f32x4 acc[4][4] = {};
    const int NKT = K >> 6;

    // prologue: 2-deep prefetch (tiles 0,1), then publish tile 0
    MSTG6(MA0, MB0); MADV;
    MSTG6(MA1, MB1); MADV;
    asm volatile("s_waitcnt vmcnt(6)" ::: "memory");
    phase_bar();

    int kt = 0;
    bf16x8 bfv[4], afv[4];
    #pragma unroll 1
    for (int kt3 = 0; kt3 < NKT; kt3 += 3) {
        MITER(MA0, MB0, MA2, MB2);
        MITER(MA1, MB1, MA0, MB0);
        MITER(MA2, MB2, MA1, MB1);
    }

    float4 bv4[4];
    #pragma unroll
    for (int ni = 0; ni < 4; ni++)
        bv4[ni] = *(const float4*)&bias[n0 + wc * 64 + ni * 16 + quad * 4];

    #pragma unroll
    for (int mi = 0; mi < 4; mi++) {
        const int m = m0 + wr * 64 + mi * 16 + l16;
        #pragma unroll
        for (int ni = 0; ni < 4; ni++) {
            const int nb2 = n0 + wc * 64 + ni * 16 + quad * 4;
            float v[4] = { acc[mi][ni][0] + bv4[ni].x, acc[mi][ni][1] + bv4[ni].y,
                           acc[mi][ni][2] + bv4[ni].z, acc[mi][ni][3] + bv4[ni].w };
            if (act) {
                #pragma unroll
                for (int r = 0; r < 4; r++) v[r] = gelu_f(v[r]);
            }
            *(uint2*)&out[(size_t)m * N + nb2] = pack4bf(v);
        }
    }
#undef MSTG6
#undef MADV
#undef MLD
#undef MMFMA
#undef MITER
}

// ---------------- MFMA GEMM 256x128 narrow-N (proj, fc2), pipelined, NAMED triple-buffer ----------------
// (round-4 winner, unchanged) fp32 residual RMW epilogue. Requires NKT % 3 == 0.
__global__ __launch_bounds__(512, 2) void gemmn128_k(const bf16* __restrict__ A, const bf16* __restrict__ BT,
                                                     const float* __restrict__ bias, float* __restrict__ x,
                                                     int N, int K, int nbn)
{
    __shared__ __align__(16) bf16 NA0[256 * 64];
    __shared__ __align__(16) bf16 NA1[256 * 64];
    __shared__ __align__(16) bf16 NA2[256 * 64];
    __shared__ __align__(16) bf16 NB0[128 * 64];
    __shared__ __align__(16) bf16 NB1[128 * 64];
    __shared__ __align__(16) bf16 NB2[128 * 64];

    const int tid  = threadIdx.x;
    const int lane = tid & 63, wid = tid >> 6;
    const int quad = lane >> 4, l16 = lane & 15;
    const int wr = wid >> 1, wc = wid & 1;
    const int cg0 = quad ^ (l16 & 7);
    const int cg1 = cg0 ^ 4;

    const int nwg  = gridDim.x;                        // multiple of 8
    const int wgid = ((int)blockIdx.x & 7) * (nwg >> 3) + ((int)blockIdx.x >> 3);
    const int mt = wgid / nbn, nt = wgid - mt * nbn;
    const int m0 = mt * 256, n0 = nt * 128;

    const int srow = wid * 8 + (lane >> 3);
    const int scg  = (lane & 7) ^ (lane >> 3);         // pre-swizzled global col-group
    const bf16* sa[4]; const bf16* sb[2];
    #pragma unroll
    for (int s = 0; s < 4; s++) sa[s] = A  + (size_t)(m0 + s * 64 + srow) * K + scg * 8;
    #pragma unroll
    for (int s = 0; s < 2; s++) sb[s] = BT + (size_t)(n0 + s * 64 + srow) * K + scg * 8;

#define NSTG6(NA, NB) { \
    gl_lds16(sa[0], &NA[(0 * 64 + wid * 8) * 64]); gl_lds16(sa[1], &NA[(1 * 64 + wid * 8) * 64]); \
    gl_lds16(sa[2], &NA[(2 * 64 + wid * 8) * 64]); gl_lds16(sa[3], &NA[(3 * 64 + wid * 8) * 64]); \
    gl_lds16(sb[0], &NB[(0 * 64 + wid * 8) * 64]); gl_lds16(sb[1], &NB[(1 * 64 + wid * 8) * 64]); }
#define NADV { _Pragma("unroll") for (int s = 0; s < 4; s++) sa[s] += 64; sb[0] += 64; sb[1] += 64; }
#define NLD(cg, NA, NB) { _Pragma("unroll") for (int i = 0; i < 4; i++) { \
    bfv[i] = __builtin_bit_cast(bf16x8, *(const uint4*)&NB[(wc * 64 + i * 16 + l16) * 64 + (cg) * 8]); \
    afv[i] = __builtin_bit_cast(bf16x8, *(const uint4*)&NA[(wr * 64 + i * 16 + l16) * 64 + (cg) * 8]); } }
#define NMFMA { _Pragma("unroll") for (int mi = 0; mi < 4; mi++) \
    _Pragma("unroll") for (int ni = 0; ni < 4; ni++) \
        acc[mi][ni] = __builtin_amdgcn_mfma_f32_16x16x32_bf16(bfv[ni], afv[mi], acc[mi][ni], 0, 0, 0); }
#define NITER(NAc, NBc, NAs, NBs) { \
    const bool pf = (kt + 2 < NKT); \
    NLD(cg0, NAc, NBc); \
    if (pf) { NSTG6(NAs, NBs); NADV; } \
    phase_bar(); \
    __builtin_amdgcn_s_setprio(1); NMFMA; __builtin_amdgcn_s_setprio(0); \
    phase_bar(); \
    NLD(cg1, NAc, NBc); \
    phase_bar(); \
    __builtin_amdgcn_s_setprio(1); NMFMA; __builtin_amdgcn_s_setprio(0); \
    if (pf)               { asm volatile("s_waitcnt vmcnt(6)" ::: "memory"); phase_bar(); } \
    else if (kt + 1 < NKT){ asm volatile("s_waitcnt vmcnt(0)" ::: "memory"); phase_bar(); } \
    kt++; \
}

    f32x4 acc[4][4] = {};
    const int NKT = K >> 6;

    // prologue: 2-deep prefetch (tiles 0,1), then publish tile 0
    NSTG6(NA0, NB0); NADV;
    NSTG6(NA1, NB1); NADV;
    asm volatile("s_waitcnt vmcnt(6)" ::: "memory");
    phase_bar();

    int kt = 0;
    bf16x8 bfv[4], afv[4];
    #pragma unroll 1
    for (int kt3 = 0; kt3 < NKT; kt3 += 3) {
        NITER(NA0, NB0, NA2, NB2);
        NITER(NA1, NB1, NA0, NB0);
        NITER(NA2, NB2, NA1, NB1);
    }

    float4 bv4[4];
    #pragma unroll
    for (int ni = 0; ni < 4; ni++)
        bv4[ni] = *(const float4*)&bias[n0 + wc * 64 + ni * 16 + quad * 4];

    #pragma unroll
    for (int mi = 0; mi < 4; mi++) {
        const int m = m0 + wr * 64 + mi * 16 + l16;
        #pragma unroll
        for (int ni = 0; ni < 4; ni++) {
            const int nb2 = n0 + wc * 64 + ni * 16 + quad * 4;
            float* xp = &x[(size_t)m * N + nb2];
            float4 xo = *(float4*)xp;
            xo.x += acc[mi][ni][0] + bv4[ni].x;
            xo.y += acc[mi][ni][1] + bv4[ni].y;
            xo.z += acc[mi][ni][2] + bv4[ni].z;
            xo.w += acc[mi][ni][3] + bv4[ni].w;
            *(float4*)xp = xo;      // one writer per element: no race
        }
    }
#undef NSTG6
#undef NADV
#undef NLD
#undef NMFMA
#undef NITER
}

// ---------------- MFMA flash attention: 128 queries/block ----------------
// grid (qt=4, h=12, b=16); block 256 = 4 waves; wave w owns queries w*32..w*32+31 (2 chunks of 16).
// Q-fragments loaded direct from global (no Ql LDS); K/V staged once per 128-key stage, feeds 2 chunks.
__global__ __launch_bounds__(256) void attn_k(const bf16* __restrict__ qkv, const int* __restrict__ mask,
                                              bf16* __restrict__ y)
{
    const int qt = blockIdx.x, h = blockIdx.y, b = blockIdx.z;
    const int qbase = qt * 128, tokb = b * 512;
    __shared__ __align__(16) unsigned short Kl[128][72];
    __shared__ __align__(16) unsigned short Vt[64][136];
    __shared__ __align__(16) unsigned short Ptq[4][16][136];
    __shared__ float mkf[128];

    const int tid = threadIdx.x, wave = tid >> 6, lane = tid & 63;
    const int quad = lane >> 4, l16 = lane & 15;

    // Q fragments for both chunks, direct from global (L2-resident)
    bf16x8 bq[2][2];
    #pragma unroll
    for (int qc = 0; qc < 2; qc++) {
        const bf16* qp = &qkv[(size_t)(tokb + qbase + wave * 32 + qc * 16 + l16) * 2304 + h * 64];
        bq[qc][0] = __builtin_bit_cast(bf16x8, *(const uint4*)(qp + quad * 8));
        bq[qc][1] = __builtin_bit_cast(bf16x8, *(const uint4*)(qp + 32 + quad * 8));
    }

    float m_i[2] = { -INFINITY, -INFINITY }, l_i[2] = { 0.f, 0.f };
    f32x4 Oacc[2][4] = {};

    const int nst = qt + 1;
    for (int s = 0; s < nst; s++) {
        const int j0 = s * 128;
        __syncthreads();    // WAR: Kl/Vt/Ptq from previous stage
        {   // stage K row-major, V transposed, pad-mask as additive -inf
            int key = tid >> 1, c0 = (tid & 1) * 32;
            const bf16* kg = &qkv[(size_t)(tokb + j0 + key) * 2304 + 768  + h * 64 + c0];
            const bf16* vg = &qkv[(size_t)(tokb + j0 + key) * 2304 + 1536 + h * 64 + c0];
            #pragma unroll
            for (int q = 0; q < 4; q++)
                *(uint4*)&Kl[key][c0 + q * 8] = *(const uint4*)(kg + q * 8);
            union { uint4 u[4]; unsigned short e[32]; } vv;
            #pragma unroll
            for (int q = 0; q < 4; q++) vv.u[q] = *(const uint4*)(vg + q * 8);
            #pragma unroll
            for (int j = 0; j < 32; j++) Vt[c0 + j][key] = vv.e[j];
            if (tid < 128) mkf[tid] = mask[b * 512 + j0 + tid] ? 0.f : -INFINITY;
        }
        __syncthreads();

        #pragma unroll
        for (int qc = 0; qc < 2; qc++) {
            const int qi = qbase + wave * 32 + qc * 16 + l16;

            // S^T = K · Q^T
            f32x4 sc[8] = {};
            #pragma unroll
            for (int kcc = 0; kcc < 8; kcc++) {
                bf16x8 af0 = __builtin_bit_cast(bf16x8, *(const uint4*)&Kl[kcc * 16 + l16][quad * 8]);
                bf16x8 af1 = __builtin_bit_cast(bf16x8, *(const uint4*)&Kl[kcc * 16 + l16][32 + quad * 8]);
                sc[kcc] = __builtin_amdgcn_mfma_f32_16x16x32_bf16(af0, bq[qc][0], sc[kcc], 0, 0, 0);
                sc[kcc] = __builtin_amdgcn_mfma_f32_16x16x32_bf16(af1, bq[qc][1], sc[kcc], 0, 0, 0);
            }

            float pv[8][4];
            float mx = -INFINITY;
            #pragma unroll
            for (int kcc = 0; kcc < 8; kcc++) {
                float4 mk4 = *(const float4*)&mkf[kcc * 16 + quad * 4];
                float mkr[4] = { mk4.x, mk4.y, mk4.z, mk4.w };
                #pragma unroll
                for (int r = 0; r < 4; r++) {
                    int krel = kcc * 16 + quad * 4 + r;
                    float sval = (j0 + krel <= qi) ? (sc[kcc][r] * 0.125f + mkr[r]) : -INFINITY;
                    pv[kcc][r] = sval;
                    mx = fmaxf(mx, sval);
                }
            }
            mx = fmaxf(mx, __shfl_xor(mx, 16, 64));
            mx = fmaxf(mx, __shfl_xor(mx, 32, 64));
            float mn = fmaxf(m_i[qc], mx);
            float alpha = (mn == -INFINITY) ? 1.f : __expf(m_i[qc] - mn);
            float lsum = 0.f;
            #pragma unroll
            for (int kcc = 0; kcc < 8; kcc++)
                #pragma unroll
                for (int r = 0; r < 4; r++) {
                    float pp = (pv[kcc][r] == -INFINITY) ? 0.f : __expf(pv[kcc][r] - mn);
                    pv[kcc][r] = pp; lsum += pp;
                }
            lsum += __shfl_xor(lsum, 16, 64);
            lsum += __shfl_xor(lsum, 32, 64);
            m_i[qc] = mn; l_i[qc] = alpha * l_i[qc] + lsum;

            #pragma unroll
            for (int kcc = 0; kcc < 8; kcc++)
                *(uint2*)&Ptq[wave][l16][kcc * 16 + quad * 4] = pack4bf(pv[kcc]);
            #pragma unroll
            for (int mc = 0; mc < 4; mc++)
                #pragma unroll
                for (int r = 0; r < 4; r++) Oacc[qc][mc][r] *= alpha;

            __syncthreads();   // uniform across waves (same qc sequence)

            #pragma unroll
            for (int kcc = 0; kcc < 4; kcc++) {
                bf16x8 pb = __builtin_bit_cast(bf16x8, *(const uint4*)&Ptq[wave][l16][kcc * 32 + quad * 8]);
                #pragma unroll
                for (int mc = 0; mc < 4; mc++) {
                    bf16x8 vf = __builtin_bit_cast(bf16x8, *(const uint4*)&Vt[mc * 16 + l16][kcc * 32 + quad * 8]);
                    Oacc[qc][mc] = __builtin_amdgcn_mfma_f32_16x16x32_bf16(vf, pb, Oacc[qc][mc], 0, 0, 0);
                }
            }
        }
    }

    #pragma unroll
    for (int qc = 0; qc < 2; qc++) {
        float inv = (l_i[qc] > 0.f) ? 1.f / l_i[qc] : 0.f;   // fully-masked row -> 0
        const int tok = tokb + qbase + wave * 32 + qc * 16 + l16;
        #pragma unroll
        for (int mc = 0; mc < 4; mc++) {
            float v[4] = { Oacc[qc][mc][0] * inv, Oacc[qc][mc][1] * inv,
                           Oacc[qc][mc][2] * inv, Oacc[qc][mc][3] * inv };
            *(uint2*)&y[(size_t)tok * 768 + h * 64 + mc * 16 + quad * 4] = pack4bf(v);
        }
    }
}

// ---------------- final LN + last-token select + head (fp32) ----------------
__global__ __launch_bounds__(256) void head_k(const float* __restrict__ x, const int* __restrict__ lastidx,
                                              const float* __restrict__ ls, const float* __restrict__ lb,
                                              const float* __restrict__ hw, const float* __restrict__ hb,
                                              float* __restrict__ out)
{
    int b = blockIdx.x, tid = threadIdx.x;
    const float* xr = x + ((size_t)(b * 512 + lastidx[b])) * 768;
    float v0 = xr[tid], v1 = xr[tid + 256], v2 = xr[tid + 512];
    __shared__ float rs[256], rq[256];
    rs[tid] = v0 + v1 + v2; rq[tid] = v0 * v0 + v1 * v1 + v2 * v2;
    __syncthreads();
    for (int st = 128; st > 0; st >>= 1) {
        if (tid < st) { rs[tid] += rs[tid + st]; rq[tid] += rq[tid + st]; }
        __syncthreads();
    }
    float mean = rs[0] * (1.f / 768.f);
    float var  = rq[0] * (1.f / 768.f) - mean * mean;
    float rstd = rsqrtf(var + 1e-5f);
    float part[9];
    #pragma unroll
    for (int a = 0; a < 9; a++) part[a] = 0.f;
    float vv[3] = { v0, v1, v2 };
    #pragma unroll
    for (int e = 0; e < 3; e++) {
        int d = tid + e * 256;
        float xnv = (vv[e] - mean) * rstd * ls[d] + lb[d];
        #pragma unroll
        for (int a = 0; a < 9; a++) part[a] += xnv * hw[d * 9 + a];
    }
    __shared__ float r9[9][256];
    #pragma unroll
    for (int a = 0; a < 9; a++) r9[a][tid] = part[a];
    __syncthreads();
    for (int st = 128; st > 0; st >>= 1) {
        if (tid < st) {
            for (int a = 0; a < 9; a++) r9[a][tid] += r9[a][tid + st];
        }
        __syncthreads();
    }
    if (tid < 9) out[b * 9 + tid] = r9[tid][0] + hb[tid];
}

extern "C" void kernel_launch(void* const* d_in, const int* in_sizes, int n_in,
                              void* d_out, int out_size, void* d_ws, size_t ws_size,
                              hipStream_t stream) {
    const int*   cards   = (const int*)  d_in[0];
    const int*   players = (const int*)  d_in[1];
    const int*   deck    = (const int*)  d_in[2];
    const int*   oppd    = (const int*)  d_in[3];
    const float* tok     = (const float*)d_in[4];
    const float* pemb    = (const float*)d_in[5];
    const float* pos     = (const float*)d_in[6];
    const float* ln1s  = (const float*)d_in[9];
    const float* ln1b  = (const float*)d_in[10];
    const float* qkvw  = (const float*)d_in[11];
    const float* qkvb  = (const float*)d_in[12];
    const float* projw = (const float*)d_in[13];
    const float* projb = (const float*)d_in[14];
    const float* ln2s  = (const float*)d_in[15];
    const float* ln2b  = (const float*)d_in[16];
    const float* fc1w  = (const float*)d_in[17];
    const float* fc1b  = (const float*)d_in[18];
    const float* fc2w  = (const float*)d_in[19];
    const float* fc2b  = (const float*)d_in[20];
    const float* lnfs  = (const float*)d_in[21];
    const float* lnfb  = (const float*)d_in[22];
    const float* hw    = (const float*)d_in[23];
    const float* hb    = (const float*)d_in[24];
    float* out = (float*)d_out;

    char* p = (char*)d_ws;
    auto alloc = [&](size_t bytes) { char* q = p; p += (bytes + 255) & ~((size_t)255); return q; };
    float* x     = (float*)alloc(8192ull * 768 * 4);
    bf16*  xn    = (bf16*) alloc(8192ull * 768 * 2);
    bf16*  big   = (bf16*) alloc(8192ull * 3072 * 2);
    bf16*  wt    = (bf16*) alloc(7077888ull * 2);      // all 4 transposed mats of one layer
    float* deckm = (float*)alloc(2ull * 16 * 768 * 4);
    int*   maskb = (int*)  alloc(8192ull * 4);
    int*   lasti = (int*)  alloc(64);

    bf16* wq = wt;                        // [2304][768]
    bf16* wp = wq + 2304ull * 768;        // [768][768]
    bf16* w1 = wp + 768ull * 768;         // [3072][768]
    bf16* w2 = w1 + 3072ull * 768;        // [768][3072]

    deckmean_k<<<dim3(16, 2), 256, 0, stream>>>(deck, oppd, tok, deckm);
    mask_k<<<16, 512, 0, stream>>>(cards, maskb, lasti);
    embed_k<<<8192, 256, 0, stream>>>(cards, players, tok, pemb, pos, deckm, x);

    for (int i = 0; i < 6; i++) {
        transpose4_k<<<1728, 256, 0, stream>>>(
            qkvw + (size_t)i * 768 * 2304, projw + (size_t)i * 768 * 768,
            fc1w + (size_t)i * 768 * 3072, fc2w + (size_t)i * 3072 * 768,
            wq, wp, w1, w2);

        // attention block
        ln_k<<<8192, 192, 0, stream>>>(x, ln1s + i * 768, ln1b + i * 768, xn);
        gemmn128b_k<<<576, 512, 0, stream>>>(xn, wq, qkvb + i * 2304, big, 2304, 768, 0, 18);
        attn_k<<<dim3(4, 12, 16), 256, 0, stream>>>(big, maskb, xn);
        gemmn128_k<<<192, 512, 0, stream>>>(xn, wp, projb + i * 768, x, 768, 768, 6);
        // MLP block
        ln_k<<<8192, 192, 0, stream>>>(x, ln2s + i * 768, ln2b + i * 768, xn);
        gemmn128b_k<<<768, 512, 0, stream>>>(xn, w1, fc1b + i * 3072, big, 3072, 768, 1, 24);
        gemmn128_k<<<192, 512, 0, stream>>>(big, w2, fc2b + i * 768, x, 768, 3072, 6);
    }

    head_k<<<16, 256, 0, stream>>>(x, lasti, lnfs, lnfb, hw, hb, out);
}

// Round 7
// 1786.924 us; speedup vs baseline: 1.1170x; 1.0691x over previous
//
#include <hip/hip_runtime.h>
#include <hip/hip_bf16.h>
#include <math.h>

typedef __hip_bfloat16 bf16;
typedef __bf16 bf16x8 __attribute__((ext_vector_type(8)));
typedef float f32x4 __attribute__((ext_vector_type(4)));

__device__ __forceinline__ float b2f(bf16 v){ return __bfloat162float(v); }
__device__ __forceinline__ bf16  f2b(float v){ return __float2bfloat16(v); }

// tanh-form gelu (~6 VALU ops); max |diff vs erf-gelu| ~1e-3
__device__ __forceinline__ float gelu_f(float v){
    float y = v * (1.f + 0.044715f * v * v);
    return v / (1.f + __expf(-1.5957691216057308f * y));
}

// async global->LDS, 16B per lane; LDS dest = wave-uniform base + lane*16
__device__ __forceinline__ void gl_lds16(const bf16* g, bf16* l) {
    __builtin_amdgcn_global_load_lds((const __attribute__((address_space(1))) unsigned int*)g,
                                     (__attribute__((address_space(3))) unsigned int*)l, 16, 0, 0);
}

__device__ __forceinline__ uint2 pack4bf(const float* v){
    union { unsigned short e[4]; uint2 u; } pk;
    #pragma unroll
    for (int r = 0; r < 4; r++) pk.e[r] = __builtin_bit_cast(unsigned short, f2b(v[r]));
    return pk.u;
}

// raw barrier without the compiler's vmcnt(0) drain; sched fences pin phase structure
__device__ __forceinline__ void phase_bar() {
    __builtin_amdgcn_sched_barrier(0);
    __builtin_amdgcn_s_barrier();
    __builtin_amdgcn_sched_barrier(0);
}

// L2-supertile block mapping: each XCD owns 4 fixed mt-panels (A stays L2-resident all dispatch),
// sweeps nt in chunks of ntc so the ~32 concurrently-resident blocks/XCD touch
// 4 A-panels + ntc B-panels < 4 MB L2. slot order within XCD: chunk-major, then mt, then nt.
__device__ __forceinline__ void supertile_map(int bid, int ntc, int& mt, int& nt) {
    const int slot = bid >> 3, xcd = bid & 7;
    const int g = 4 * ntc;
    const int chunk = slot / g;
    const int r = slot - chunk * g;
    const int ml = r / ntc;
    mt = xcd * 4 + ml;
    nt = chunk * ntc + (r - ml * ntc);
}

// ---------------- deck means ----------------
__global__ __launch_bounds__(256) void deckmean_k(const int* __restrict__ deck, const int* __restrict__ opp,
                                                  const float* __restrict__ tok, float* __restrict__ deckm)
{
    int b = blockIdx.x, w = blockIdx.y;
    const int* dk = (w ? opp : deck) + b * 8;
    int idx[8];
    #pragma unroll
    for (int j = 0; j < 8; j++) idx[j] = dk[j];
    float* out = deckm + (size_t)(w * 16 + b) * 768;
    for (int d = threadIdx.x; d < 768; d += 256) {
        float s = 0.f;
        #pragma unroll
        for (int j = 0; j < 8; j++) s += tok[(size_t)idx[j] * 768 + d];
        out[d] = s * 0.125f;
    }
}

// ---------------- mask + last_idx ----------------
__global__ __launch_bounds__(512) void mask_k(const int* __restrict__ cards, int* __restrict__ maskb,
                                              int* __restrict__ lastidx)
{
    int b = blockIdx.x, t = threadIdx.x;
    int m = (cards[b * 512 + t] != 0) ? 1 : 0;
    maskb[b * 512 + t] = m;
    __shared__ int red[512];
    red[t] = m; __syncthreads();
    for (int st = 256; st > 0; st >>= 1) { if (t < st) red[t] += red[t + st]; __syncthreads(); }
    if (t == 0) {
        int cnt = red[0];
        if (cnt == 0) { maskb[b * 512] = 1; cnt = 1; }  // all-pad fix
        lastidx[b] = cnt - 1;
    }
}

// ---------------- embedding sum -> fp32 residual stream ----------------
__global__ __launch_bounds__(256) void embed_k(const int* __restrict__ cards, const int* __restrict__ players,
                                               const float* __restrict__ tok, const float* __restrict__ pemb,
                                               const float* __restrict__ pos, const float* __restrict__ deckm,
                                               float* __restrict__ x)
{
    int t = blockIdx.x;
    int b = t >> 9, ti = t & 511;
    int cd = cards[t];
    int p = players[t]; p = p < 0 ? 0 : (p > 1 ? 1 : p);
    const float* tr  = tok  + (size_t)cd * 768;
    const float* pr  = pemb + (size_t)p  * 768;
    const float* po  = pos  + (size_t)ti * 768;
    const float* dm = deckm + (size_t)b * 768;
    const float* om = deckm + (size_t)(16 + b) * 768;
    float* xr = x + (size_t)t * 768;
    for (int d = threadIdx.x; d < 768; d += 256)
        xr[d] = tr[d] + pr[d] + po[d] + dm[d] + om[d];
}

// ---------------- layernorm (vectorized): fp32 in -> bf16 out, 192 thr/row ----------------
__global__ __launch_bounds__(192) void ln_k(const float* __restrict__ x, const float* __restrict__ s,
                                            const float* __restrict__ b, bf16* __restrict__ out)
{
    int row = blockIdx.x, tid = threadIdx.x;
    float4 v = ((const float4*)(x + (size_t)row * 768))[tid];
    float sum = v.x + v.y + v.z + v.w;
    float sq  = v.x * v.x + v.y * v.y + v.z * v.z + v.w * v.w;
    #pragma unroll
    for (int off = 32; off > 0; off >>= 1) {
        sum += __shfl_xor(sum, off, 64);
        sq  += __shfl_xor(sq,  off, 64);
    }
    __shared__ float red[6];
    int wv = tid >> 6;
    if ((tid & 63) == 0) { red[wv] = sum; red[3 + wv] = sq; }
    __syncthreads();
    float S = red[0] + red[1] + red[2];
    float Q = red[3] + red[4] + red[5];
    float mean = S * (1.f / 768.f);
    float var  = Q * (1.f / 768.f) - mean * mean;
    float rstd = rsqrtf(var + 1e-5f);
    float4 sv = ((const float4*)s)[tid];
    float4 bv = ((const float4*)b)[tid];
    float o[4] = { (v.x - mean) * rstd * sv.x + bv.x, (v.y - mean) * rstd * sv.y + bv.y,
                   (v.z - mean) * rstd * sv.z + bv.z, (v.w - mean) * rstd * sv.w + bv.w };
    ((uint2*)(out + (size_t)row * 768))[tid] = pack4bf(o);
}

// ---------------- weight transpose+downcast: 64x64 tiles, in-register 4x4 transpose ----------------
// tiles: qkv 12x36=432, proj 12x12=144, fc1 12x48=576, fc2 48x12=576 -> 1728 blocks
__global__ __launch_bounds__(256) void transpose4_k(const float* __restrict__ qw, const float* __restrict__ pw,
                                                    const float* __restrict__ f1, const float* __restrict__ f2,
                                                    bf16* __restrict__ oq, bf16* __restrict__ op,
                                                    bf16* __restrict__ o1, bf16* __restrict__ o2)
{
    int t = blockIdx.x;
    const float* in; bf16* out; int K, N, nbx;
    if (t < 432)       { in = qw; out = oq; K = 768;  N = 2304; nbx = 36; }
    else if (t < 576)  { in = pw; out = op; K = 768;  N = 768;  t -= 432;  nbx = 12; }
    else if (t < 1152) { in = f1; out = o1; K = 768;  N = 3072; t -= 576;  nbx = 48; }
    else               { in = f2; out = o2; K = 3072; N = 768;  t -= 1152; nbx = 12; }
    int n0 = (t % nbx) * 64, k0 = (t / nbx) * 64;
    int kq = threadIdx.x & 15, nq = threadIdx.x >> 4;
    float4 rr[4];
    #pragma unroll
    for (int r = 0; r < 4; r++)
        rr[r] = *(const float4*)&in[(size_t)(k0 + kq * 4 + r) * N + n0 + nq * 4];
    const float* fp = (const float*)rr;
    #pragma unroll
    for (int c = 0; c < 4; c++) {
        float v[4] = { fp[c], fp[4 + c], fp[8 + c], fp[12 + c] };
        *(uint2*)&out[(size_t)(n0 + nq * 4 + c) * K + k0 + kq * 4] = pack4bf(v);
    }
}

// ---------------- MFMA GEMM 256x128 (qkv, fc1): named triple-buffer + counted vmcnt, bf16 out ----------------
// Round-4/5 winning structure + L2-supertile mapping (mt fixed per XCD -> A L2-resident all dispatch).
// 512 thr = 8 waves (4M x 2N), per-wave 64x64 = acc[4][4]; 2 phases x 16 MFMA per K-tile.
// Requires NKT % 3 == 0 (K=768 -> 12).
__global__ __launch_bounds__(512, 2) void gemmn128b_k(const bf16* __restrict__ A, const bf16* __restrict__ BT,
                                                      const float* __restrict__ bias, bf16* __restrict__ out,
                                                      int N, int K, int act, int ntc)
{
    __shared__ __align__(16) bf16 MA0[256 * 64];
    __shared__ __align__(16) bf16 MA1[256 * 64];
    __shared__ __align__(16) bf16 MA2[256 * 64];
    __shared__ __align__(16) bf16 MB0[128 * 64];
    __shared__ __align__(16) bf16 MB1[128 * 64];
    __shared__ __align__(16) bf16 MB2[128 * 64];

    const int tid  = threadIdx.x;
    const int lane = tid & 63, wid = tid >> 6;
    const int quad = lane >> 4, l16 = lane & 15;
    const int wr = wid >> 1, wc = wid & 1;
    const int cg0 = quad ^ (l16 & 7);
    const int cg1 = cg0 ^ 4;

    int mt, nt;
    supertile_map((int)blockIdx.x, ntc, mt, nt);
    const int m0 = mt * 256, n0 = nt * 128;

    const int srow = wid * 8 + (lane >> 3);
    const int scg  = (lane & 7) ^ (lane >> 3);         // pre-swizzled global col-group
    const bf16* sa[4]; const bf16* sb[2];
    #pragma unroll
    for (int s = 0; s < 4; s++) sa[s] = A  + (size_t)(m0 + s * 64 + srow) * K + scg * 8;
    #pragma unroll
    for (int s = 0; s < 2; s++) sb[s] = BT + (size_t)(n0 + s * 64 + srow) * K + scg * 8;

#define MSTG6(NA, NB) { \
    gl_lds16(sa[0], &NA[(0 * 64 + wid * 8) * 64]); gl_lds16(sa[1], &NA[(1 * 64 + wid * 8) * 64]); \
    gl_lds16(sa[2], &NA[(2 * 64 + wid * 8) * 64]); gl_lds16(sa[3], &NA[(3 * 64 + wid * 8) * 64]); \
    gl_lds16(sb[0], &NB[(0 * 64 + wid * 8) * 64]); gl_lds16(sb[1], &NB[(1 * 64 + wid * 8) * 64]); }
#define MADV { _Pragma("unroll") for (int s = 0; s < 4; s++) sa[s] += 64; sb[0] += 64; sb[1] += 64; }
#define MLD(cg, NA, NB) { _Pragma("unroll") for (int i = 0; i < 4; i++) { \
    bfv[i] = __builtin_bit_cast(bf16x8, *(const uint4*)&NB[(wc * 64 + i * 16 + l16) * 64 + (cg) * 8]); \
    afv[i] = __builtin_bit_cast(bf16x8, *(const uint4*)&NA[(wr * 64 + i * 16 + l16) * 64 + (cg) * 8]); } }
#define MMFMA { _Pragma("unroll") for (int mi = 0; mi < 4; mi++) \
    _Pragma("unroll") for (int ni = 0; ni < 4; ni++) \
        acc[mi][ni] = __builtin_amdgcn_mfma_f32_16x16x32_bf16(bfv[ni], afv[mi], acc[mi][ni], 0, 0, 0); }
#define MITER(NAc, NBc, NAs, NBs) { \
    const bool pf = (kt + 2 < NKT); \
    MLD(cg0, NAc, NBc); \
    if (pf) { MSTG6(NAs, NBs); MADV; } \
    phase_bar(); \
    __builtin_amdgcn_s_setprio(1); MMFMA; __builtin_amdgcn_s_setprio(0); \
    phase_bar(); \
    MLD(cg1, NAc, NBc); \
    phase_bar(); \
    __builtin_amdgcn_s_setprio(1); MMFMA; __builtin_amdgcn_s_setprio(0); \
    if (pf)               { asm volatile("s_waitcnt vmcnt(6)" ::: "memory"); phase_bar(); } \
    else if (kt + 1 < NKT){ asm volatile("s_waitcnt vmcnt(0)" ::: "memory"); phase_bar(); } \
    kt++; \
}

    f32x4 acc[4][4] = {};
    const int NKT = K >> 6;

    // prologue: 2-deep prefetch (tiles 0,1), then publish tile 0
    MSTG6(MA0, MB0); MADV;
    MSTG6(MA1, MB1); MADV;
    asm volatile("s_waitcnt vmcnt(6)" ::: "memory");
    phase_bar();

    int kt = 0;
    bf16x8 bfv[4], afv[4];
    #pragma unroll 1
    for (int kt3 = 0; kt3 < NKT; kt3 += 3) {
        MITER(MA0, MB0, MA2, MB2);
        MITER(MA1, MB1, MA0, MB0);
        MITER(MA2, MB2, MA1, MB1);
    }

    float4 bv4[4];
    #pragma unroll
    for (int ni = 0; ni < 4; ni++)
        bv4[ni] = *(const float4*)&bias[n0 + wc * 64 + ni * 16 + quad * 4];

    #pragma unroll
    for (int mi = 0; mi < 4; mi++) {
        const int m = m0 + wr * 64 + mi * 16 + l16;
        #pragma unroll
        for (int ni = 0; ni < 4; ni++) {
            const int nb2 = n0 + wc * 64 + ni * 16 + quad * 4;
            float v[4] = { acc[mi][ni][0] + bv4[ni].x, acc[mi][ni][1] + bv4[ni].y,
                           acc[mi][ni][2] + bv4[ni].z, acc[mi][ni][3] + bv4[ni].w };
            if (act) {
                #pragma unroll
                for (int r = 0; r < 4; r++) v[r] = gelu_f(v[r]);
            }
            *(uint2*)&out[(size_t)m * N + nb2] = pack4bf(v);
        }
    }
#undef MSTG6
#undef MADV
#undef MLD
#undef MMFMA
#undef MITER
}

// ---------------- MFMA GEMM 256x128 narrow-N (proj, fc2), pipelined, NAMED triple-buffer ----------------
// (round-4 winner + L2-supertile mapping) fp32 residual RMW epilogue. Requires NKT % 3 == 0.
__global__ __launch_bounds__(512, 2) void gemmn128_k(const bf16* __restrict__ A, const bf16* __restrict__ BT,
                                                     const float* __restrict__ bias, float* __restrict__ x,
                                                     int N, int K, int ntc)
{
    __shared__ __align__(16) bf16 NA0[256 * 64];
    __shared__ __align__(16) bf16 NA1[256 * 64];
    __shared__ __align__(16) bf16 NA2[256 * 64];
    __shared__ __align__(16) bf16 NB0[128 * 64];
    __shared__ __align__(16) bf16 NB1[128 * 64];
    __shared__ __align__(16) bf16 NB2[128 * 64];

    const int tid  = threadIdx.x;
    const int lane = tid & 63, wid = tid >> 6;
    const int quad = lane >> 4, l16 = lane & 15;
    const int wr = wid >> 1, wc = wid & 1;
    const int cg0 = quad ^ (l16 & 7);
    const int cg1 = cg0 ^ 4;

    int mt, nt;
    supertile_map((int)blockIdx.x, ntc, mt, nt);
    const int m0 = mt * 256, n0 = nt * 128;

    const int srow = wid * 8 + (lane >> 3);
    const int scg  = (lane & 7) ^ (lane >> 3);         // pre-swizzled global col-group
    const bf16* sa[4]; const bf16* sb[2];
    #pragma unroll
    for (int s = 0; s < 4; s++) sa[s] = A  + (size_t)(m0 + s * 64 + srow) * K + scg * 8;
    #pragma unroll
    for (int s = 0; s < 2; s++) sb[s] = BT + (size_t)(n0 + s * 64 + srow) * K + scg * 8;

#define NSTG6(NA, NB) { \
    gl_lds16(sa[0], &NA[(0 * 64 + wid * 8) * 64]); gl_lds16(sa[1], &NA[(1 * 64 + wid * 8) * 64]); \
    gl_lds16(sa[2], &NA[(2 * 64 + wid * 8) * 64]); gl_lds16(sa[3], &NA[(3 * 64 + wid * 8) * 64]); \
    gl_lds16(sb[0], &NB[(0 * 64 + wid * 8) * 64]); gl_lds16(sb[1], &NB[(1 * 64 + wid * 8) * 64]); }
#define NADV { _Pragma("unroll") for (int s = 0; s < 4; s++) sa[s] += 64; sb[0] += 64; sb[1] += 64; }
#define NLD(cg, NA, NB) { _Pragma("unroll") for (int i = 0; i < 4; i++) { \
    bfv[i] = __builtin_bit_cast(bf16x8, *(const uint4*)&NB[(wc * 64 + i * 16 + l16) * 64 + (cg) * 8]); \
    afv[i] = __builtin_bit_cast(bf16x8, *(const uint4*)&NA[(wr * 64 + i * 16 + l16) * 64 + (cg) * 8]); } }
#define NMFMA { _Pragma("unroll") for (int mi = 0; mi < 4; mi++) \
    _Pragma("unroll") for (int ni = 0; ni < 4; ni++) \
        acc[mi][ni] = __builtin_amdgcn_mfma_f32_16x16x32_bf16(bfv[ni], afv[mi], acc[mi][ni], 0, 0, 0); }
#define NITER(NAc, NBc, NAs, NBs) { \
    const bool pf = (kt + 2 < NKT); \
    NLD(cg0, NAc, NBc); \
    if (pf) { NSTG6(NAs, NBs); NADV; } \
    phase_bar(); \
    __builtin_amdgcn_s_setprio(1); NMFMA; __builtin_amdgcn_s_setprio(0); \
    phase_bar(); \
    NLD(cg1, NAc, NBc); \
    phase_bar(); \
    __builtin_amdgcn_s_setprio(1); NMFMA; __builtin_amdgcn_s_setprio(0); \
    if (pf)               { asm volatile("s_waitcnt vmcnt(6)" ::: "memory"); phase_bar(); } \
    else if (kt + 1 < NKT){ asm volatile("s_waitcnt vmcnt(0)" ::: "memory"); phase_bar(); } \
    kt++; \
}

    f32x4 acc[4][4] = {};
    const int NKT = K >> 6;

    // prologue: 2-deep prefetch (tiles 0,1), then publish tile 0
    NSTG6(NA0, NB0); NADV;
    NSTG6(NA1, NB1); NADV;
    asm volatile("s_waitcnt vmcnt(6)" ::: "memory");
    phase_bar();

    int kt = 0;
    bf16x8 bfv[4], afv[4];
    #pragma unroll 1
    for (int kt3 = 0; kt3 < NKT; kt3 += 3) {
        NITER(NA0, NB0, NA2, NB2);
        NITER(NA1, NB1, NA0, NB0);
        NITER(NA2, NB2, NA1, NB1);
    }

    float4 bv4[4];
    #pragma unroll
    for (int ni = 0; ni < 4; ni++)
        bv4[ni] = *(const float4*)&bias[n0 + wc * 64 + ni * 16 + quad * 4];

    #pragma unroll
    for (int mi = 0; mi < 4; mi++) {
        const int m = m0 + wr * 64 + mi * 16 + l16;
        #pragma unroll
        for (int ni = 0; ni < 4; ni++) {
            const int nb2 = n0 + wc * 64 + ni * 16 + quad * 4;
            float* xp = &x[(size_t)m * N + nb2];
            float4 xo = *(float4*)xp;
            xo.x += acc[mi][ni][0] + bv4[ni].x;
            xo.y += acc[mi][ni][1] + bv4[ni].y;
            xo.z += acc[mi][ni][2] + bv4[ni].z;
            xo.w += acc[mi][ni][3] + bv4[ni].w;
            *(float4*)xp = xo;      // one writer per element: no race
        }
    }
#undef NSTG6
#undef NADV
#undef NLD
#undef NMFMA
#undef NITER
}

// ---------------- MFMA flash attention: 128 queries/block ----------------
// grid (qt=4, h=12, b=16); block 256 = 4 waves; wave w owns queries w*32..w*32+31 (2 chunks of 16).
// Q-fragments loaded direct from global (no Ql LDS); K/V staged once per 128-key stage, feeds 2 chunks.
__global__ __launch_bounds__(256) void attn_k(const bf16* __restrict__ qkv, const int* __restrict__ mask,
                                              bf16* __restrict__ y)
{
    const int qt = blockIdx.x, h = blockIdx.y, b = blockIdx.z;
    const int qbase = qt * 128, tokb = b * 512;
    __shared__ __align__(16) unsigned short Kl[128][72];
    __shared__ __align__(16) unsigned short Vt[64][136];
    __shared__ __align__(16) unsigned short Ptq[4][16][136];
    __shared__ float mkf[128];

    const int tid = threadIdx.x, wave = tid >> 6, lane = tid & 63;
    const int quad = lane >> 4, l16 = lane & 15;

    // Q fragments for both chunks, direct from global (L2-resident)
    bf16x8 bq[2][2];
    #pragma unroll
    for (int qc = 0; qc < 2; qc++) {
        const bf16* qp = &qkv[(size_t)(tokb + qbase + wave * 32 + qc * 16 + l16) * 2304 + h * 64];
        bq[qc][0] = __builtin_bit_cast(bf16x8, *(const uint4*)(qp + quad * 8));
        bq[qc][1] = __builtin_bit_cast(bf16x8, *(const uint4*)(qp + 32 + quad * 8));
    }

    float m_i[2] = { -INFINITY, -INFINITY }, l_i[2] = { 0.f, 0.f };
    f32x4 Oacc[2][4] = {};

    const int nst = qt + 1;
    for (int s = 0; s < nst; s++) {
        const int j0 = s * 128;
        __syncthreads();    // WAR: Kl/Vt/Ptq from previous stage
        {   // stage K row-major, V transposed, pad-mask as additive -inf
            int key = tid >> 1, c0 = (tid & 1) * 32;
            const bf16* kg = &qkv[(size_t)(tokb + j0 + key) * 2304 + 768  + h * 64 + c0];
            const bf16* vg = &qkv[(size_t)(tokb + j0 + key) * 2304 + 1536 + h * 64 + c0];
            #pragma unroll
            for (int q = 0; q < 4; q++)
                *(uint4*)&Kl[key][c0 + q * 8] = *(const uint4*)(kg + q * 8);
            union { uint4 u[4]; unsigned short e[32]; } vv;
            #pragma unroll
            for (int q = 0; q < 4; q++) vv.u[q] = *(const uint4*)(vg + q * 8);
            #pragma unroll
            for (int j = 0; j < 32; j++) Vt[c0 + j][key] = vv.e[j];
            if (tid < 128) mkf[tid] = mask[b * 512 + j0 + tid] ? 0.f : -INFINITY;
        }
        __syncthreads();

        #pragma unroll
        for (int qc = 0; qc < 2; qc++) {
            const int qi = qbase + wave * 32 + qc * 16 + l16;

            // S^T = K · Q^T
            f32x4 sc[8] = {};
            #pragma unroll
            for (int kcc = 0; kcc < 8; kcc++) {
                bf16x8 af0 = __builtin_bit_cast(bf16x8, *(const uint4*)&Kl[kcc * 16 + l16][quad * 8]);
                bf16x8 af1 = __builtin_bit_cast(bf16x8, *(const uint4*)&Kl[kcc * 16 + l16][32 + quad * 8]);
                sc[kcc] = __builtin_amdgcn_mfma_f32_16x16x32_bf16(af0, bq[qc][0], sc[kcc], 0, 0, 0);
                sc[kcc] = __builtin_amdgcn_mfma_f32_16x16x32_bf16(af1, bq[qc][1], sc[kcc], 0, 0, 0);
            }

            float pv[8][4];
            float mx = -INFINITY;
            #pragma unroll
            for (int kcc = 0; kcc < 8; kcc++) {
                float4 mk4 = *(const float4*)&mkf[kcc * 16 + quad * 4];
                float mkr[4] = { mk4.x, mk4.y, mk4.z, mk4.w };
                #pragma unroll
                for (int r = 0; r < 4; r++) {
                    int krel = kcc * 16 + quad * 4 + r;
                    float sval = (j0 + krel <= qi) ? (sc[kcc][r] * 0.125f + mkr[r]) : -INFINITY;
                    pv[kcc][r] = sval;
                    mx = fmaxf(mx, sval);
                }
            }
            mx = fmaxf(mx, __shfl_xor(mx, 16, 64));
            mx = fmaxf(mx, __shfl_xor(mx, 32, 64));
            float mn = fmaxf(m_i[qc], mx);
            float alpha = (mn == -INFINITY) ? 1.f : __expf(m_i[qc] - mn);
            float lsum = 0.f;
            #pragma unroll
            for (int kcc = 0; kcc < 8; kcc++)
                #pragma unroll
                for (int r = 0; r < 4; r++) {
                    float pp = (pv[kcc][r] == -INFINITY) ? 0.f : __expf(pv[kcc][r] - mn);
                    pv[kcc][r] = pp; lsum += pp;
                }
            lsum += __shfl_xor(lsum, 16, 64);
            lsum += __shfl_xor(lsum, 32, 64);
            m_i[qc] = mn; l_i[qc] = alpha * l_i[qc] + lsum;

            #pragma unroll
            for (int kcc = 0; kcc < 8; kcc++)
                *(uint2*)&Ptq[wave][l16][kcc * 16 + quad * 4] = pack4bf(pv[kcc]);
            #pragma unroll
            for (int mc = 0; mc < 4; mc++)
                #pragma unroll
                for (int r = 0; r < 4; r++) Oacc[qc][mc][r] *= alpha;

            __syncthreads();   // uniform across waves (same qc sequence)

            #pragma unroll
            for (int kcc = 0; kcc < 4; kcc++) {
                bf16x8 pb = __builtin_bit_cast(bf16x8, *(const uint4*)&Ptq[wave][l16][kcc * 32 + quad * 8]);
                #pragma unroll
                for (int mc = 0; mc < 4; mc++) {
                    bf16x8 vf = __builtin_bit_cast(bf16x8, *(const uint4*)&Vt[mc * 16 + l16][kcc * 32 + quad * 8]);
                    Oacc[qc][mc] = __builtin_amdgcn_mfma_f32_16x16x32_bf16(vf, pb, Oacc[qc][mc], 0, 0, 0);
                }
            }
        }
    }

    #pragma unroll
    for (int qc = 0; qc < 2; qc++) {
        float inv = (l_i[qc] > 0.f) ? 1.f / l_i[qc] : 0.f;   // fully-masked row -> 0
        const int tok = tokb + qbase + wave * 32 + qc * 16 + l16;
        #pragma unroll
        for (int mc = 0; mc < 4; mc++) {
            float v[4] = { Oacc[qc][mc][0] * inv, Oacc[qc][mc][1] * inv,
                           Oacc[qc][mc][2] * inv, Oacc[qc][mc][3] * inv };
            *(uint2*)&y[(size_t)tok * 768 + h * 64 + mc * 16 + quad * 4] = pack4bf(v);
        }
    }
}

// ---------------- final LN + last-token select + head (fp32) ----------------
__global__ __launch_bounds__(256) void head_k(const float* __restrict__ x, const int* __restrict__ lastidx,
                                              const float* __restrict__ ls, const float* __restrict__ lb,
                                              const float* __restrict__ hw, const float* __restrict__ hb,
                                              float* __restrict__ out)
{
    int b = blockIdx.x, tid = threadIdx.x;
    const float* xr = x + ((size_t)(b * 512 + lastidx[b])) * 768;
    float v0 = xr[tid], v1 = xr[tid + 256], v2 = xr[tid + 512];
    __shared__ float rs[256], rq[256];
    rs[tid] = v0 + v1 + v2; rq[tid] = v0 * v0 + v1 * v1 + v2 * v2;
    __syncthreads();
    for (int st = 128; st > 0; st >>= 1) {
        if (tid < st) { rs[tid] += rs[tid + st]; rq[tid] += rq[tid + st]; }
        __syncthreads();
    }
    float mean = rs[0] * (1.f / 768.f);
    float var  = rq[0] * (1.f / 768.f) - mean * mean;
    float rstd = rsqrtf(var + 1e-5f);
    float part[9];
    #pragma unroll
    for (int a = 0; a < 9; a++) part[a] = 0.f;
    float vv[3] = { v0, v1, v2 };
    #pragma unroll
    for (int e = 0; e < 3; e++) {
        int d = tid + e * 256;
        float xnv = (vv[e] - mean) * rstd * ls[d] + lb[d];
        #pragma unroll
        for (int a = 0; a < 9; a++) part[a] += xnv * hw[d * 9 + a];
    }
    __shared__ float r9[9][256];
    #pragma unroll
    for (int a = 0; a < 9; a++) r9[a][tid] = part[a];
    __syncthreads();
    for (int st = 128; st > 0; st >>= 1) {
        if (tid < st) {
            for (int a = 0; a < 9; a++) r9[a][tid] += r9[a][tid + st];
        }
        __syncthreads();
    }
    if (tid < 9) out[b * 9 + tid] = r9[tid][0] + hb[tid];
}

extern "C" void kernel_launch(void* const* d_in, const int* in_sizes, int n_in,
                              void* d_out, int out_size, void* d_ws, size_t ws_size,
                              hipStream_t stream) {
    const int*   cards   = (const int*)  d_in[0];
    const int*   players = (const int*)  d_in[1];
    const int*   deck    = (const int*)  d_in[2];
    const int*   oppd    = (const int*)  d_in[3];
    const float* tok     = (const float*)d_in[4];
    const float* pemb    = (const float*)d_in[5];
    const float* pos     = (const float*)d_in[6];
    const float* ln1s  = (const float*)d_in[9];
    const float* ln1b  = (const float*)d_in[10];
    const float* qkvw  = (const float*)d_in[11];
    const float* qkvb  = (const float*)d_in[12];
    const float* projw = (const float*)d_in[13];
    const float* projb = (const float*)d_in[14];
    const float* ln2s  = (const float*)d_in[15];
    const float* ln2b  = (const float*)d_in[16];
    const float* fc1w  = (const float*)d_in[17];
    const float* fc1b  = (const float*)d_in[18];
    const float* fc2w  = (const float*)d_in[19];
    const float* fc2b  = (const float*)d_in[20];
    const float* lnfs  = (const float*)d_in[21];
    const float* lnfb  = (const float*)d_in[22];
    const float* hw    = (const float*)d_in[23];
    const float* hb    = (const float*)d_in[24];
    float* out = (float*)d_out;

    char* p = (char*)d_ws;
    auto alloc = [&](size_t bytes) { char* q = p; p += (bytes + 255) & ~((size_t)255); return q; };
    float* x     = (float*)alloc(8192ull * 768 * 4);
    bf16*  xn    = (bf16*) alloc(8192ull * 768 * 2);
    bf16*  big   = (bf16*) alloc(8192ull * 3072 * 2);
    bf16*  wt    = (bf16*) alloc(7077888ull * 2);      // all 4 transposed mats of one layer
    float* deckm = (float*)alloc(2ull * 16 * 768 * 4);
    int*   maskb = (int*)  alloc(8192ull * 4);
    int*   lasti = (int*)  alloc(64);

    bf16* wq = wt;                        // [2304][768]
    bf16* wp = wq + 2304ull * 768;        // [768][768]
    bf16* w1 = wp + 768ull * 768;         // [3072][768]
    bf16* w2 = w1 + 3072ull * 768;        // [768][3072]

    deckmean_k<<<dim3(16, 2), 256, 0, stream>>>(deck, oppd, tok, deckm);
    mask_k<<<16, 512, 0, stream>>>(cards, maskb, lasti);
    embed_k<<<8192, 256, 0, stream>>>(cards, players, tok, pemb, pos, deckm, x);

    for (int i = 0; i < 6; i++) {
        transpose4_k<<<1728, 256, 0, stream>>>(
            qkvw + (size_t)i * 768 * 2304, projw + (size_t)i * 768 * 768,
            fc1w + (size_t)i * 768 * 3072, fc2w + (size_t)i * 3072 * 768,
            wq, wp, w1, w2);

        // attention block
        ln_k<<<8192, 192, 0, stream>>>(x, ln1s + i * 768, ln1b + i * 768, xn);
        gemmn128b_k<<<576, 512, 0, stream>>>(xn, wq, qkvb + i * 2304, big, 2304, 768, 0, 6);
        attn_k<<<dim3(4, 12, 16), 256, 0, stream>>>(big, maskb, xn);
        gemmn128_k<<<192, 512, 0, stream>>>(xn, wp, projb + i * 768, x, 768, 768, 6);
        // MLP block
        ln_k<<<8192, 192, 0, stream>>>(x, ln2s + i * 768, ln2b + i * 768, xn);
        gemmn128b_k<<<768, 512, 0, stream>>>(xn, w1, fc1b + i * 3072, big, 3072, 768, 1, 8);
        gemmn128_k<<<192, 512, 0, stream>>>(big, w2, fc2b + i * 768, x, 768, 3072, 6);
    }

    head_k<<<16, 256, 0, stream>>>(x, lasti, lnfs, lnfb, hw, hb, out);
}

// Round 8
// 1674.707 us; speedup vs baseline: 1.1918x; 1.0670x over previous
//
#include <hip/hip_runtime.h>
#include <hip/hip_bf16.h>
#include <math.h>

typedef __hip_bfloat16 bf16;
typedef __bf16 bf16x8 __attribute__((ext_vector_type(8)));
typedef float f32x4 __attribute__((ext_vector_type(4)));

__device__ __forceinline__ float b2f(bf16 v){ return __bfloat162float(v); }
__device__ __forceinline__ bf16  f2b(float v){ return __float2bfloat16(v); }

// tanh-form gelu (~6 VALU ops); max |diff vs erf-gelu| ~1e-3
__device__ __forceinline__ float gelu_f(float v){
    float y = v * (1.f + 0.044715f * v * v);
    return v / (1.f + __expf(-1.5957691216057308f * y));
}

// async global->LDS, 16B per lane; LDS dest = wave-uniform base + lane*16
__device__ __forceinline__ void gl_lds16(const bf16* g, bf16* l) {
    __builtin_amdgcn_global_load_lds((const __attribute__((address_space(1))) unsigned int*)g,
                                     (__attribute__((address_space(3))) unsigned int*)l, 16, 0, 0);
}

__device__ __forceinline__ uint2 pack4bf(const float* v){
    union { unsigned short e[4]; uint2 u; } pk;
    #pragma unroll
    for (int r = 0; r < 4; r++) pk.e[r] = __builtin_bit_cast(unsigned short, f2b(v[r]));
    return pk.u;
}

// raw barrier without the compiler's vmcnt(0) drain; sched fences pin phase structure
__device__ __forceinline__ void phase_bar() {
    __builtin_amdgcn_sched_barrier(0);
    __builtin_amdgcn_s_barrier();
    __builtin_amdgcn_sched_barrier(0);
}

// L2-supertile block mapping (BM=256 kernels): each XCD owns 4 fixed mt-panels,
// sweeps nt in chunks of ntc. slot order within XCD: chunk-major, then mt, then nt.
__device__ __forceinline__ void supertile_map(int bid, int ntc, int& mt, int& nt) {
    const int slot = bid >> 3, xcd = bid & 7;
    const int g = 4 * ntc;
    const int chunk = slot / g;
    const int r = slot - chunk * g;
    const int ml = r / ntc;
    mt = xcd * 4 + ml;
    nt = chunk * ntc + (r - ml * ntc);
}

// BM=128 variant: each XCD owns 8 fixed mt-panels (64 total), nt chunks of ntc.
__device__ __forceinline__ void supertile_map8(int bid, int ntc, int& mt, int& nt) {
    const int slot = bid >> 3, xcd = bid & 7;
    const int g = 8 * ntc;
    const int chunk = slot / g;
    const int r = slot - chunk * g;
    const int ml = r / ntc;
    mt = xcd * 8 + ml;
    nt = chunk * ntc + (r - ml * ntc);
}

// ---------------- deck means ----------------
__global__ __launch_bounds__(256) void deckmean_k(const int* __restrict__ deck, const int* __restrict__ opp,
                                                  const float* __restrict__ tok, float* __restrict__ deckm)
{
    int b = blockIdx.x, w = blockIdx.y;
    const int* dk = (w ? opp : deck) + b * 8;
    int idx[8];
    #pragma unroll
    for (int j = 0; j < 8; j++) idx[j] = dk[j];
    float* out = deckm + (size_t)(w * 16 + b) * 768;
    for (int d = threadIdx.x; d < 768; d += 256) {
        float s = 0.f;
        #pragma unroll
        for (int j = 0; j < 8; j++) s += tok[(size_t)idx[j] * 768 + d];
        out[d] = s * 0.125f;
    }
}

// ---------------- mask + last_idx ----------------
__global__ __launch_bounds__(512) void mask_k(const int* __restrict__ cards, int* __restrict__ maskb,
                                              int* __restrict__ lastidx)
{
    int b = blockIdx.x, t = threadIdx.x;
    int m = (cards[b * 512 + t] != 0) ? 1 : 0;
    maskb[b * 512 + t] = m;
    __shared__ int red[512];
    red[t] = m; __syncthreads();
    for (int st = 256; st > 0; st >>= 1) { if (t < st) red[t] += red[t + st]; __syncthreads(); }
    if (t == 0) {
        int cnt = red[0];
        if (cnt == 0) { maskb[b * 512] = 1; cnt = 1; }  // all-pad fix
        lastidx[b] = cnt - 1;
    }
}

// ---------------- embedding sum -> fp32 residual stream ----------------
__global__ __launch_bounds__(256) void embed_k(const int* __restrict__ cards, const int* __restrict__ players,
                                               const float* __restrict__ tok, const float* __restrict__ pemb,
                                               const float* __restrict__ pos, const float* __restrict__ deckm,
                                               float* __restrict__ x)
{
    int t = blockIdx.x;
    int b = t >> 9, ti = t & 511;
    int cd = cards[t];
    int p = players[t]; p = p < 0 ? 0 : (p > 1 ? 1 : p);
    const float* tr  = tok  + (size_t)cd * 768;
    const float* pr  = pemb + (size_t)p  * 768;
    const float* po  = pos  + (size_t)ti * 768;
    const float* dm = deckm + (size_t)b * 768;
    const float* om = deckm + (size_t)(16 + b) * 768;
    float* xr = x + (size_t)t * 768;
    for (int d = threadIdx.x; d < 768; d += 256)
        xr[d] = tr[d] + pr[d] + po[d] + dm[d] + om[d];
}

// ---------------- layernorm (vectorized): fp32 in -> bf16 out, 192 thr/row ----------------
__global__ __launch_bounds__(192) void ln_k(const float* __restrict__ x, const float* __restrict__ s,
                                            const float* __restrict__ b, bf16* __restrict__ out)
{
    int row = blockIdx.x, tid = threadIdx.x;
    float4 v = ((const float4*)(x + (size_t)row * 768))[tid];
    float sum = v.x + v.y + v.z + v.w;
    float sq  = v.x * v.x + v.y * v.y + v.z * v.z + v.w * v.w;
    #pragma unroll
    for (int off = 32; off > 0; off >>= 1) {
        sum += __shfl_xor(sum, off, 64);
        sq  += __shfl_xor(sq,  off, 64);
    }
    __shared__ float red[6];
    int wv = tid >> 6;
    if ((tid & 63) == 0) { red[wv] = sum; red[3 + wv] = sq; }
    __syncthreads();
    float S = red[0] + red[1] + red[2];
    float Q = red[3] + red[4] + red[5];
    float mean = S * (1.f / 768.f);
    float var  = Q * (1.f / 768.f) - mean * mean;
    float rstd = rsqrtf(var + 1e-5f);
    float4 sv = ((const float4*)s)[tid];
    float4 bv = ((const float4*)b)[tid];
    float o[4] = { (v.x - mean) * rstd * sv.x + bv.x, (v.y - mean) * rstd * sv.y + bv.y,
                   (v.z - mean) * rstd * sv.z + bv.z, (v.w - mean) * rstd * sv.w + bv.w };
    ((uint2*)(out + (size_t)row * 768))[tid] = pack4bf(o);
}

// ---------------- weight transpose+downcast: 64x64 tiles, in-register 4x4 transpose ----------------
// tiles: qkv 12x36=432, proj 12x12=144, fc1 12x48=576, fc2 48x12=576 -> 1728 blocks
__global__ __launch_bounds__(256) void transpose4_k(const float* __restrict__ qw, const float* __restrict__ pw,
                                                    const float* __restrict__ f1, const float* __restrict__ f2,
                                                    bf16* __restrict__ oq, bf16* __restrict__ op,
                                                    bf16* __restrict__ o1, bf16* __restrict__ o2)
{
    int t = blockIdx.x;
    const float* in; bf16* out; int K, N, nbx;
    if (t < 432)       { in = qw; out = oq; K = 768;  N = 2304; nbx = 36; }
    else if (t < 576)  { in = pw; out = op; K = 768;  N = 768;  t -= 432;  nbx = 12; }
    else if (t < 1152) { in = f1; out = o1; K = 768;  N = 3072; t -= 576;  nbx = 48; }
    else               { in = f2; out = o2; K = 3072; N = 768;  t -= 1152; nbx = 12; }
    int n0 = (t % nbx) * 64, k0 = (t / nbx) * 64;
    int kq = threadIdx.x & 15, nq = threadIdx.x >> 4;
    float4 rr[4];
    #pragma unroll
    for (int r = 0; r < 4; r++)
        rr[r] = *(const float4*)&in[(size_t)(k0 + kq * 4 + r) * N + n0 + nq * 4];
    const float* fp = (const float*)rr;
    #pragma unroll
    for (int c = 0; c < 4; c++) {
        float v[4] = { fp[c], fp[4 + c], fp[8 + c], fp[12 + c] };
        *(uint2*)&out[(size_t)(n0 + nq * 4 + c) * K + k0 + kq * 4] = pack4bf(v);
    }
}

// ---------------- MFMA GEMM 128x128 TLP (qkv, fc1): 2 blocks/CU, named double-buffer, bf16 out ----
// 256 thr = 4 waves (2M x 2N), per-wave 64x64 = acc[4][4]; 32 MFMA per K-tile.
// LDS 64 KB (DA0/DA1/DB0/DB1 16KB each) -> 2 blocks/CU: TLP hides the depth-1 vmcnt(0) drain
// (the co-resident block computes while this one waits). One correctness barrier per tile.
// Named buffers + compile-time selection keep the waitcnt pass alias-precise (round-4 finding).
// Requires NKT even (K=768 -> 12).
__global__ __launch_bounds__(256, 2) void gemm2b_k(const bf16* __restrict__ A, const bf16* __restrict__ BT,
                                                   const float* __restrict__ bias, bf16* __restrict__ out,
                                                   int N, int K, int act, int ntc)
{
    __shared__ __align__(16) bf16 DA0[128 * 64];
    __shared__ __align__(16) bf16 DA1[128 * 64];
    __shared__ __align__(16) bf16 DB0[128 * 64];
    __shared__ __align__(16) bf16 DB1[128 * 64];

    const int tid  = threadIdx.x;
    const int lane = tid & 63, wid = tid >> 6;        // 4 waves
    const int quad = lane >> 4, l16 = lane & 15;
    const int wr = wid >> 1, wc = wid & 1;
    const int cg0 = quad ^ (l16 & 7);
    const int cg1 = cg0 ^ 4;

    int mt, nt;
    supertile_map8((int)blockIdx.x, ntc, mt, nt);
    const int m0 = mt * 128, n0 = nt * 128;

    // staging: 256 lanes x 16B = 32 rows per gl_lds sweep; 4 sweeps each for A,B
    const int srow = wid * 8 + (lane >> 3);           // [0,32)
    const int scg  = (lane & 7) ^ (lane >> 3);        // pre-swizzled global col-group
    const bf16* sa[4]; const bf16* sb[4];
    #pragma unroll
    for (int s = 0; s < 4; s++) {
        sa[s] = A  + (size_t)(m0 + s * 32 + srow) * K + scg * 8;
        sb[s] = BT + (size_t)(n0 + s * 32 + srow) * K + scg * 8;
    }

#define D_STG8(NA, NB) { \
    gl_lds16(sa[0], &NA[(0 * 32 + wid * 8) * 64]); gl_lds16(sa[1], &NA[(1 * 32 + wid * 8) * 64]); \
    gl_lds16(sa[2], &NA[(2 * 32 + wid * 8) * 64]); gl_lds16(sa[3], &NA[(3 * 32 + wid * 8) * 64]); \
    gl_lds16(sb[0], &NB[(0 * 32 + wid * 8) * 64]); gl_lds16(sb[1], &NB[(1 * 32 + wid * 8) * 64]); \
    gl_lds16(sb[2], &NB[(2 * 32 + wid * 8) * 64]); gl_lds16(sb[3], &NB[(3 * 32 + wid * 8) * 64]); }
#define D_ADV { _Pragma("unroll") for (int s = 0; s < 4; s++) { sa[s] += 64; sb[s] += 64; } }
#define D_LD(cg, NA, NB) { _Pragma("unroll") for (int i = 0; i < 4; i++) { \
    bfv[i] = __builtin_bit_cast(bf16x8, *(const uint4*)&NB[(wc * 64 + i * 16 + l16) * 64 + (cg) * 8]); \
    afv[i] = __builtin_bit_cast(bf16x8, *(const uint4*)&NA[(wr * 64 + i * 16 + l16) * 64 + (cg) * 8]); } }
#define D_MFMA { _Pragma("unroll") for (int mi = 0; mi < 4; mi++) \
    _Pragma("unroll") for (int ni = 0; ni < 4; ni++) \
        acc[mi][ni] = __builtin_amdgcn_mfma_f32_16x16x32_bf16(bfv[ni], afv[mi], acc[mi][ni], 0, 0, 0); }
// one K-tile: {ds_read cg0 | stage kt+1}, MFMA16, {ds_read cg1}, MFMA16, wait, bar
#define D_TILE(DAc, DBc, DAn, DBn) { \
    const bool pf = (kt + 1 < NKT); \
    D_LD(cg0, DAc, DBc); \
    if (pf) { D_STG8(DAn, DBn); D_ADV; } \
    __builtin_amdgcn_s_setprio(1); D_MFMA; __builtin_amdgcn_s_setprio(0); \
    D_LD(cg1, DAc, DBc); \
    __builtin_amdgcn_s_setprio(1); D_MFMA; __builtin_amdgcn_s_setprio(0); \
    if (pf) { asm volatile("s_waitcnt vmcnt(0)" ::: "memory"); } \
    phase_bar(); \
    kt++; \
}

    f32x4 acc[4][4] = {};
    const int NKT = K >> 6;

    // prologue: stage tile 0 -> DA0/DB0
    D_STG8(DA0, DB0); D_ADV;
    asm volatile("s_waitcnt vmcnt(0)" ::: "memory");
    phase_bar();

    int kt = 0;
    bf16x8 bfv[4], afv[4];
    #pragma unroll 1
    for (int kt2 = 0; kt2 < NKT; kt2 += 2) {
        D_TILE(DA0, DB0, DA1, DB1);
        D_TILE(DA1, DB1, DA0, DB0);
    }

    float4 bv4[4];
    #pragma unroll
    for (int ni = 0; ni < 4; ni++)
        bv4[ni] = *(const float4*)&bias[n0 + wc * 64 + ni * 16 + quad * 4];

    #pragma unroll
    for (int mi = 0; mi < 4; mi++) {
        const int m = m0 + wr * 64 + mi * 16 + l16;
        #pragma unroll
        for (int ni = 0; ni < 4; ni++) {
            const int nb2 = n0 + wc * 64 + ni * 16 + quad * 4;
            float v[4] = { acc[mi][ni][0] + bv4[ni].x, acc[mi][ni][1] + bv4[ni].y,
                           acc[mi][ni][2] + bv4[ni].z, acc[mi][ni][3] + bv4[ni].w };
            if (act) {
                #pragma unroll
                for (int r = 0; r < 4; r++) v[r] = gelu_f(v[r]);
            }
            *(uint2*)&out[(size_t)m * N + nb2] = pack4bf(v);
        }
    }
#undef D_STG8
#undef D_ADV
#undef D_LD
#undef D_MFMA
#undef D_TILE
}

// ---------------- MFMA GEMM 256x128 narrow-N (proj, fc2), pipelined, NAMED triple-buffer ----------------
// (round-7 kernel, unchanged) fp32 residual RMW epilogue. Requires NKT % 3 == 0.
__global__ __launch_bounds__(512, 2) void gemmn128_k(const bf16* __restrict__ A, const bf16* __restrict__ BT,
                                                     const float* __restrict__ bias, float* __restrict__ x,
                                                     int N, int K, int ntc)
{
    __shared__ __align__(16) bf16 NA0[256 * 64];
    __shared__ __align__(16) bf16 NA1[256 * 64];
    __shared__ __align__(16) bf16 NA2[256 * 64];
    __shared__ __align__(16) bf16 NB0[128 * 64];
    __shared__ __align__(16) bf16 NB1[128 * 64];
    __shared__ __align__(16) bf16 NB2[128 * 64];

    const int tid  = threadIdx.x;
    const int lane = tid & 63, wid = tid >> 6;
    const int quad = lane >> 4, l16 = lane & 15;
    const int wr = wid >> 1, wc = wid & 1;
    const int cg0 = quad ^ (l16 & 7);
    const int cg1 = cg0 ^ 4;

    int mt, nt;
    supertile_map((int)blockIdx.x, ntc, mt, nt);
    const int m0 = mt * 256, n0 = nt * 128;

    const int srow = wid * 8 + (lane >> 3);
    const int scg  = (lane & 7) ^ (lane >> 3);         // pre-swizzled global col-group
    const bf16* sa[4]; const bf16* sb[2];
    #pragma unroll
    for (int s = 0; s < 4; s++) sa[s] = A  + (size_t)(m0 + s * 64 + srow) * K + scg * 8;
    #pragma unroll
    for (int s = 0; s < 2; s++) sb[s] = BT + (size_t)(n0 + s * 64 + srow) * K + scg * 8;

#define NSTG6(NA, NB) { \
    gl_lds16(sa[0], &NA[(0 * 64 + wid * 8) * 64]); gl_lds16(sa[1], &NA[(1 * 64 + wid * 8) * 64]); \
    gl_lds16(sa[2], &NA[(2 * 64 + wid * 8) * 64]); gl_lds16(sa[3], &NA[(3 * 64 + wid * 8) * 64]); \
    gl_lds16(sb[0], &NB[(0 * 64 + wid * 8) * 64]); gl_lds16(sb[1], &NB[(1 * 64 + wid * 8) * 64]); }
#define NADV { _Pragma("unroll") for (int s = 0; s < 4; s++) sa[s] += 64; sb[0] += 64; sb[1] += 64; }
#define NLD(cg, NA, NB) { _Pragma("unroll") for (int i = 0; i < 4; i++) { \
    bfv[i] = __builtin_bit_cast(bf16x8, *(const uint4*)&NB[(wc * 64 + i * 16 + l16) * 64 + (cg) * 8]); \
    afv[i] = __builtin_bit_cast(bf16x8, *(const uint4*)&NA[(wr * 64 + i * 16 + l16) * 64 + (cg) * 8]); } }
#define NMFMA { _Pragma("unroll") for (int mi = 0; mi < 4; mi++) \
    _Pragma("unroll") for (int ni = 0; ni < 4; ni++) \
        acc[mi][ni] = __builtin_amdgcn_mfma_f32_16x16x32_bf16(bfv[ni], afv[mi], acc[mi][ni], 0, 0, 0); }
#define NITER(NAc, NBc, NAs, NBs) { \
    const bool pf = (kt + 2 < NKT); \
    NLD(cg0, NAc, NBc); \
    if (pf) { NSTG6(NAs, NBs); NADV; } \
    phase_bar(); \
    __builtin_amdgcn_s_setprio(1); NMFMA; __builtin_amdgcn_s_setprio(0); \
    phase_bar(); \
    NLD(cg1, NAc, NBc); \
    phase_bar(); \
    __builtin_amdgcn_s_setprio(1); NMFMA; __builtin_amdgcn_s_setprio(0); \
    if (pf)               { asm volatile("s_waitcnt vmcnt(6)" ::: "memory"); phase_bar(); } \
    else if (kt + 1 < NKT){ asm volatile("s_waitcnt vmcnt(0)" ::: "memory"); phase_bar(); } \
    kt++; \
}

    f32x4 acc[4][4] = {};
    const int NKT = K >> 6;

    // prologue: 2-deep prefetch (tiles 0,1), then publish tile 0
    NSTG6(NA0, NB0); NADV;
    NSTG6(NA1, NB1); NADV;
    asm volatile("s_waitcnt vmcnt(6)" ::: "memory");
    phase_bar();

    int kt = 0;
    bf16x8 bfv[4], afv[4];
    #pragma unroll 1
    for (int kt3 = 0; kt3 < NKT; kt3 += 3) {
        NITER(NA0, NB0, NA2, NB2);
        NITER(NA1, NB1, NA0, NB0);
        NITER(NA2, NB2, NA1, NB1);
    }

    float4 bv4[4];
    #pragma unroll
    for (int ni = 0; ni < 4; ni++)
        bv4[ni] = *(const float4*)&bias[n0 + wc * 64 + ni * 16 + quad * 4];

    #pragma unroll
    for (int mi = 0; mi < 4; mi++) {
        const int m = m0 + wr * 64 + mi * 16 + l16;
        #pragma unroll
        for (int ni = 0; ni < 4; ni++) {
            const int nb2 = n0 + wc * 64 + ni * 16 + quad * 4;
            float* xp = &x[(size_t)m * N + nb2];
            float4 xo = *(float4*)xp;
            xo.x += acc[mi][ni][0] + bv4[ni].x;
            xo.y += acc[mi][ni][1] + bv4[ni].y;
            xo.z += acc[mi][ni][2] + bv4[ni].z;
            xo.w += acc[mi][ni][3] + bv4[ni].w;
            *(float4*)xp = xo;      // one writer per element: no race
        }
    }
#undef NSTG6
#undef NADV
#undef NLD
#undef NMFMA
#undef NITER
}

// ---------------- MFMA flash attention: 128 queries/block ----------------
// grid (qt=4, h=12, b=16); block 256 = 4 waves; wave w owns queries w*32..w*32+31 (2 chunks of 16).
// Q-fragments loaded direct from global (no Ql LDS); K/V staged once per 128-key stage, feeds 2 chunks.
__global__ __launch_bounds__(256) void attn_k(const bf16* __restrict__ qkv, const int* __restrict__ mask,
                                              bf16* __restrict__ y)
{
    const int qt = blockIdx.x, h = blockIdx.y, b = blockIdx.z;
    const int qbase = qt * 128, tokb = b * 512;
    __shared__ __align__(16) unsigned short Kl[128][72];
    __shared__ __align__(16) unsigned short Vt[64][136];
    __shared__ __align__(16) unsigned short Ptq[4][16][136];
    __shared__ float mkf[128];

    const int tid = threadIdx.x, wave = tid >> 6, lane = tid & 63;
    const int quad = lane >> 4, l16 = lane & 15;

    // Q fragments for both chunks, direct from global (L2-resident)
    bf16x8 bq[2][2];
    #pragma unroll
    for (int qc = 0; qc < 2; qc++) {
        const bf16* qp = &qkv[(size_t)(tokb + qbase + wave * 32 + qc * 16 + l16) * 2304 + h * 64];
        bq[qc][0] = __builtin_bit_cast(bf16x8, *(const uint4*)(qp + quad * 8));
        bq[qc][1] = __builtin_bit_cast(bf16x8, *(const uint4*)(qp + 32 + quad * 8));
    }

    float m_i[2] = { -INFINITY, -INFINITY }, l_i[2] = { 0.f, 0.f };
    f32x4 Oacc[2][4] = {};

    const int nst = qt + 1;
    for (int s = 0; s < nst; s++) {
        const int j0 = s * 128;
        __syncthreads();    // WAR: Kl/Vt/Ptq from previous stage
        {   // stage K row-major, V transposed, pad-mask as additive -inf
            int key = tid >> 1, c0 = (tid & 1) * 32;
            const bf16* kg = &qkv[(size_t)(tokb + j0 + key) * 2304 + 768  + h * 64 + c0];
            const bf16* vg = &qkv[(size_t)(tokb + j0 + key) * 2304 + 1536 + h * 64 + c0];
            #pragma unroll
            for (int q = 0; q < 4; q++)
                *(uint4*)&Kl[key][c0 + q * 8] = *(const uint4*)(kg + q * 8);
            union { uint4 u[4]; unsigned short e[32]; } vv;
            #pragma unroll
            for (int q = 0; q < 4; q++) vv.u[q] = *(const uint4*)(vg + q * 8);
            #pragma unroll
            for (int j = 0; j < 32; j++) Vt[c0 + j][key] = vv.e[j];
            if (tid < 128) mkf[tid] = mask[b * 512 + j0 + tid] ? 0.f : -INFINITY;
        }
        __syncthreads();

        #pragma unroll
        for (int qc = 0; qc < 2; qc++) {
            const int qi = qbase + wave * 32 + qc * 16 + l16;

            // S^T = K · Q^T
            f32x4 sc[8] = {};
            #pragma unroll
            for (int kcc = 0; kcc < 8; kcc++) {
                bf16x8 af0 = __builtin_bit_cast(bf16x8, *(const uint4*)&Kl[kcc * 16 + l16][quad * 8]);
                bf16x8 af1 = __builtin_bit_cast(bf16x8, *(const uint4*)&Kl[kcc * 16 + l16][32 + quad * 8]);
                sc[kcc] = __builtin_amdgcn_mfma_f32_16x16x32_bf16(af0, bq[qc][0], sc[kcc], 0, 0, 0);
                sc[kcc] = __builtin_amdgcn_mfma_f32_16x16x32_bf16(af1, bq[qc][1], sc[kcc], 0, 0, 0);
            }

            float pv[8][4];
            float mx = -INFINITY;
            #pragma unroll
            for (int kcc = 0; kcc < 8; kcc++) {
                float4 mk4 = *(const float4*)&mkf[kcc * 16 + quad * 4];
                float mkr[4] = { mk4.x, mk4.y, mk4.z, mk4.w };
                #pragma unroll
                for (int r = 0; r < 4; r++) {
                    int krel = kcc * 16 + quad * 4 + r;
                    float sval = (j0 + krel <= qi) ? (sc[kcc][r] * 0.125f + mkr[r]) : -INFINITY;
                    pv[kcc][r] = sval;
                    mx = fmaxf(mx, sval);
                }
            }
            mx = fmaxf(mx, __shfl_xor(mx, 16, 64));
            mx = fmaxf(mx, __shfl_xor(mx, 32, 64));
            float mn = fmaxf(m_i[qc], mx);
            float alpha = (mn == -INFINITY) ? 1.f : __expf(m_i[qc] - mn);
            float lsum = 0.f;
            #pragma unroll
            for (int kcc = 0; kcc < 8; kcc++)
                #pragma unroll
                for (int r = 0; r < 4; r++) {
                    float pp = (pv[kcc][r] == -INFINITY) ? 0.f : __expf(pv[kcc][r] - mn);
                    pv[kcc][r] = pp; lsum += pp;
                }
            lsum += __shfl_xor(lsum, 16, 64);
            lsum += __shfl_xor(lsum, 32, 64);
            m_i[qc] = mn; l_i[qc] = alpha * l_i[qc] + lsum;

            #pragma unroll
            for (int kcc = 0; kcc < 8; kcc++)
                *(uint2*)&Ptq[wave][l16][kcc * 16 + quad * 4] = pack4bf(pv[kcc]);
            #pragma unroll
            for (int mc = 0; mc < 4; mc++)
                #pragma unroll
                for (int r = 0; r < 4; r++) Oacc[qc][mc][r] *= alpha;

            __syncthreads();   // uniform across waves (same qc sequence)

            #pragma unroll
            for (int kcc = 0; kcc < 4; kcc++) {
                bf16x8 pb = __builtin_bit_cast(bf16x8, *(const uint4*)&Ptq[wave][l16][kcc * 32 + quad * 8]);
                #pragma unroll
                for (int mc = 0; mc < 4; mc++) {
                    bf16x8 vf = __builtin_bit_cast(bf16x8, *(const uint4*)&Vt[mc * 16 + l16][kcc * 32 + quad * 8]);
                    Oacc[qc][mc] = __builtin_amdgcn_mfma_f32_16x16x32_bf16(vf, pb, Oacc[qc][mc], 0, 0, 0);
                }
            }
        }
    }

    #pragma unroll
    for (int qc = 0; qc < 2; qc++) {
        float inv = (l_i[qc] > 0.f) ? 1.f / l_i[qc] : 0.f;   // fully-masked row -> 0
        const int tok = tokb + qbase + wave * 32 + qc * 16 + l16;
        #pragma unroll
        for (int mc = 0; mc < 4; mc++) {
            float v[4] = { Oacc[qc][mc][0] * inv, Oacc[qc][mc][1] * inv,
                           Oacc[qc][mc][2] * inv, Oacc[qc][mc][3] * inv };
            *(uint2*)&y[(size_t)tok * 768 + h * 64 + mc * 16 + quad * 4] = pack4bf(v);
        }
    }
}

// ---------------- final LN + last-token select + head (fp32) ----------------
__global__ __launch_bounds__(256) void head_k(const float* __restrict__ x, const int* __restrict__ lastidx,
                                              const float* __restrict__ ls, const float* __restrict__ lb,
                                              const float* __restrict__ hw, const float* __restrict__ hb,
                                              float* __restrict__ out)
{
    int b = blockIdx.x, tid = threadIdx.x;
    const float* xr = x + ((size_t)(b * 512 + lastidx[b])) * 768;
    float v0 = xr[tid], v1 = xr[tid + 256], v2 = xr[tid + 512];
    __shared__ float rs[256], rq[256];
    rs[tid] = v0 + v1 + v2; rq[tid] = v0 * v0 + v1 * v1 + v2 * v2;
    __syncthreads();
    for (int st = 128; st > 0; st >>= 1) {
        if (tid < st) { rs[tid] += rs[tid + st]; rq[tid] += rq[tid + st]; }
        __syncthreads();
    }
    float mean = rs[0] * (1.f / 768.f);
    float var  = rq[0] * (1.f / 768.f) - mean * mean;
    float rstd = rsqrtf(var + 1e-5f);
    float part[9];
    #pragma unroll
    for (int a = 0; a < 9; a++) part[a] = 0.f;
    float vv[3] = { v0, v1, v2 };
    #pragma unroll
    for (int e = 0; e < 3; e++) {
        int d = tid + e * 256;
        float xnv = (vv[e] - mean) * rstd * ls[d] + lb[d];
        #pragma unroll
        for (int a = 0; a < 9; a++) part[a] += xnv * hw[d * 9 + a];
    }
    __shared__ float r9[9][256];
    #pragma unroll
    for (int a = 0; a < 9; a++) r9[a][tid] = part[a];
    __syncthreads();
    for (int st = 128; st > 0; st >>= 1) {
        if (tid < st) {
            for (int a = 0; a < 9; a++) r9[a][tid] += r9[a][tid + st];
        }
        __syncthreads();
    }
    if (tid < 9) out[b * 9 + tid] = r9[tid][0] + hb[tid];
}

extern "C" void kernel_launch(void* const* d_in, const int* in_sizes, int n_in,
                              void* d_out, int out_size, void* d_ws, size_t ws_size,
                              hipStream_t stream) {
    const int*   cards   = (const int*)  d_in[0];
    const int*   players = (const int*)  d_in[1];
    const int*   deck    = (const int*)  d_in[2];
    const int*   oppd    = (const int*)  d_in[3];
    const float* tok     = (const float*)d_in[4];
    const float* pemb    = (const float*)d_in[5];
    const float* pos     = (const float*)d_in[6];
    const float* ln1s  = (const float*)d_in[9];
    const float* ln1b  = (const float*)d_in[10];
    const float* qkvw  = (const float*)d_in[11];
    const float* qkvb  = (const float*)d_in[12];
    const float* projw = (const float*)d_in[13];
    const float* projb = (const float*)d_in[14];
    const float* ln2s  = (const float*)d_in[15];
    const float* ln2b  = (const float*)d_in[16];
    const float* fc1w  = (const float*)d_in[17];
    const float* fc1b  = (const float*)d_in[18];
    const float* fc2w  = (const float*)d_in[19];
    const float* fc2b  = (const float*)d_in[20];
    const float* lnfs  = (const float*)d_in[21];
    const float* lnfb  = (const float*)d_in[22];
    const float* hw    = (const float*)d_in[23];
    const float* hb    = (const float*)d_in[24];
    float* out = (float*)d_out;

    char* p = (char*)d_ws;
    auto alloc = [&](size_t bytes) { char* q = p; p += (bytes + 255) & ~((size_t)255); return q; };
    float* x     = (float*)alloc(8192ull * 768 * 4);
    bf16*  xn    = (bf16*) alloc(8192ull * 768 * 2);
    bf16*  big   = (bf16*) alloc(8192ull * 3072 * 2);
    bf16*  wt    = (bf16*) alloc(7077888ull * 2);      // all 4 transposed mats of one layer
    float* deckm = (float*)alloc(2ull * 16 * 768 * 4);
    int*   maskb = (int*)  alloc(8192ull * 4);
    int*   lasti = (int*)  alloc(64);

    bf16* wq = wt;                        // [2304][768]
    bf16* wp = wq + 2304ull * 768;        // [768][768]
    bf16* w1 = wp + 768ull * 768;         // [3072][768]
    bf16* w2 = w1 + 3072ull * 768;        // [768][3072]

    deckmean_k<<<dim3(16, 2), 256, 0, stream>>>(deck, oppd, tok, deckm);
    mask_k<<<16, 512, 0, stream>>>(cards, maskb, lasti);
    embed_k<<<8192, 256, 0, stream>>>(cards, players, tok, pemb, pos, deckm, x);

    for (int i = 0; i < 6; i++) {
        transpose4_k<<<1728, 256, 0, stream>>>(
            qkvw + (size_t)i * 768 * 2304, projw + (size_t)i * 768 * 768,
            fc1w + (size_t)i * 768 * 3072, fc2w + (size_t)i * 3072 * 768,
            wq, wp, w1, w2);

        // attention block
        ln_k<<<8192, 192, 0, stream>>>(x, ln1s + i * 768, ln1b + i * 768, xn);
        gemm2b_k<<<1152, 256, 0, stream>>>(xn, wq, qkvb + i * 2304, big, 2304, 768, 0, 6);
        attn_k<<<dim3(4, 12, 16), 256, 0, stream>>>(big, maskb, xn);
        gemmn128_k<<<192, 512, 0, stream>>>(xn, wp, projb + i * 768, x, 768, 768, 6);
        // MLP block
        ln_k<<<8192, 192, 0, stream>>>(x, ln2s + i * 768, ln2b + i * 768, xn);
        gemm2b_k<<<1536, 256, 0, stream>>>(xn, w1, fc1b + i * 3072, big, 3072, 768, 1, 8);
        gemmn128_k<<<192, 512, 0, stream>>>(big, w2, fc2b + i * 768, x, 768, 3072, 6);
    }

    head_k<<<16, 256, 0, stream>>>(x, lasti, lnfs, lnfb, hw, hb, out);
}